// Round 1
// baseline (207.226 us; speedup 1.0000x reference)
//
#include <hip/hip_runtime.h>

typedef __bf16 bf16x8 __attribute__((ext_vector_type(8)));
typedef unsigned short u16x8 __attribute__((ext_vector_type(8)));
typedef u16x8 u16x8_a __attribute__((may_alias));
typedef unsigned int u32x4 __attribute__((ext_vector_type(4)));
typedef u32x4 u32x4_a __attribute__((may_alias));
typedef float f32x4 __attribute__((ext_vector_type(4)));

#define LOG2E 1.4426950408889634f
#define NEGV  -10000.0f

__device__ __forceinline__ float bf2f(unsigned short u){
  union{unsigned int i; float f;} x; x.i = ((unsigned int)u)<<16; return x.f;
}
__device__ __forceinline__ unsigned short f2bf(float f){
  union{float f; unsigned int i;} x; x.f=f;
  unsigned int i = x.i;
  return (unsigned short)((i + 0x7FFFu + ((i>>16)&1u)) >> 16);
}
__device__ __forceinline__ u16x8 cvt8(float4 a, float4 b){
  u16x8 r;
  r[0]=f2bf(a.x); r[1]=f2bf(a.y); r[2]=f2bf(a.z); r[3]=f2bf(a.w);
  r[4]=f2bf(b.x); r[5]=f2bf(b.y); r[6]=f2bf(b.z); r[7]=f2bf(b.w);
  return r;
}
__device__ __forceinline__ bf16x8 ldb(const unsigned short* p){
  return __builtin_bit_cast(bf16x8, *(const u16x8_a*)p);
}

// ---------------- weight transpose+cast: wT[g][n][k] = bf16(w[g][k][n]), 768x768 ----------------
__global__ __launch_bounds__(256) void transpose6(
    const float* __restrict__ w0, const float* __restrict__ w1,
    const float* __restrict__ w2, const float* __restrict__ w3,
    const float* __restrict__ w4, const float* __restrict__ w5,
    unsigned short* __restrict__ outT)
{
  const float* src;
  switch (blockIdx.z){
    case 0: src = w0; break; case 1: src = w1; break; case 2: src = w2; break;
    case 3: src = w3; break; case 4: src = w4; break; default: src = w5; break;
  }
  unsigned short* dst = outT + (size_t)blockIdx.z * 589824;
  __shared__ float tile[32][33];
  int tx = threadIdx.x, ty = threadIdx.y;
  int x0 = blockIdx.x*32, y0 = blockIdx.y*32;
  #pragma unroll
  for (int i=0;i<32;i+=8) tile[ty+i][tx] = src[(size_t)(y0+ty+i)*768 + x0+tx];
  __syncthreads();
  #pragma unroll
  for (int i=0;i<32;i+=8) dst[(size_t)(x0+ty+i)*768 + y0+tx] = f2bf(tile[tx][ty+i]);
}

// ---------------- V transpose: VbT[d][key] = Vb[key][d] (bf16, 2176x768 -> 768x2176) ----
__global__ __launch_bounds__(256) void transpose_v(
    const unsigned short* __restrict__ Vb, unsigned short* __restrict__ VbT)
{
  __shared__ unsigned short t[32][33];
  int tx = threadIdx.x, ty = threadIdx.y;
  int x0 = blockIdx.x*32;   // key
  int y0 = blockIdx.y*32;   // dim
  #pragma unroll
  for (int i=0;i<32;i+=8) t[ty+i][tx] = Vb[(size_t)(x0+ty+i)*768 + y0+tx];
  __syncthreads();
  #pragma unroll
  for (int i=0;i<32;i+=8) VbT[(size_t)(y0+ty+i)*2176 + x0+tx] = t[tx][ty+i];
}

// ---------------- batched projection GEMM: out = bf16(A fp32) @ wT(bf16) + bias(fp32) ----------------
__global__ __launch_bounds__(256) void gemm_proj(
    const float* __restrict__ word, const float* __restrict__ ent,
    const unsigned short* __restrict__ wT,
    const float* __restrict__ bK, const float* __restrict__ bV,
    const float* __restrict__ bQ, const float* __restrict__ bWE,
    const float* __restrict__ bEW, const float* __restrict__ bEE,
    unsigned short* __restrict__ oK, unsigned short* __restrict__ oV,
    unsigned short* __restrict__ oQ, unsigned short* __restrict__ oWE,
    unsigned short* __restrict__ oEW, unsigned short* __restrict__ oEE)
{
  int mt = blockIdx.x, ntile = blockIdx.y;
  int g, mg;
  if      (mt < 17){ g=0; mg=mt;    }
  else if (mt < 34){ g=1; mg=mt-17; }
  else if (mt < 50){ g=2; mg=mt-34; }
  else if (mt < 66){ g=3; mg=mt-50; }
  else if (mt < 67){ g=4; mg=0;     }
  else             { g=5; mg=0;     }
  int m0 = mg*128;
  const float* A;
  if (g<=1)      A = (mg<16) ? (word + (size_t)m0*768) : ent;
  else if (g<=3) A = word + (size_t)m0*768;
  else           A = ent;
  const unsigned short* B = wT + (size_t)g*589824;
  const float* bias; unsigned short* out;
  switch (g){
    case 0: bias=bK;  out=oK;  break;
    case 1: bias=bV;  out=oV;  break;
    case 2: bias=bQ;  out=oQ;  break;
    case 3: bias=bWE; out=oWE; break;
    case 4: bias=bEW; out=oEW; break;
    default:bias=bEE; out=oEE; break;
  }
  out += (size_t)m0*768;
  int n0 = ntile*128;

  __shared__ __align__(16) unsigned short a_s[128*32];
  __shared__ __align__(16) unsigned short b_s[128*32];

  int tid  = threadIdx.x;
  int w    = tid>>6, lane = tid&63, quad = lane>>4, lr = lane&15;
  int wm   = (w&1)*64, wn = (w>>1)*64;

  f32x4 acc[4][4];
  #pragma unroll
  for (int i=0;i<4;i++) for (int j=0;j<4;j++) for (int r=0;r<4;r++) acc[i][j][r]=0.f;

  int ar = tid>>1;
  int ak = (tid&1)*16;
  const float* Arow = A + (size_t)ar*768 + ak;
  const unsigned short* Brow = B + (size_t)(n0+ar)*768 + ak;

  for (int k0=0; k0<768; k0+=32){
    float4 af0 = *(const float4*)(Arow + k0);
    float4 af1 = *(const float4*)(Arow + k0 + 4);
    float4 af2 = *(const float4*)(Arow + k0 + 8);
    float4 af3 = *(const float4*)(Arow + k0 + 12);
    u16x8 av0 = cvt8(af0, af1);
    u16x8 av1 = cvt8(af2, af3);
    u16x8 bv0 = *(const u16x8_a*)(Brow + k0);
    u16x8 bv1 = *(const u16x8_a*)(Brow + k0 + 8);
    __syncthreads();
    *(u16x8_a*)(a_s + ar*32 + ak)     = av0;
    *(u16x8_a*)(a_s + ar*32 + ak + 8) = av1;
    *(u16x8_a*)(b_s + ar*32 + ak)     = bv0;
    *(u16x8_a*)(b_s + ar*32 + ak + 8) = bv1;
    __syncthreads();
    bf16x8 af[4], bfr[4];
    #pragma unroll
    for (int i=0;i<4;i++) af[i]  = ldb(a_s + (wm+i*16+lr)*32 + quad*8);
    #pragma unroll
    for (int i=0;i<4;i++) bfr[i] = ldb(b_s + (wn+i*16+lr)*32 + quad*8);
    #pragma unroll
    for (int i=0;i<4;i++)
      #pragma unroll
      for (int j=0;j<4;j++)
        acc[i][j] = __builtin_amdgcn_mfma_f32_16x16x32_bf16(af[i], bfr[j], acc[i][j], 0,0,0);
  }
  #pragma unroll
  for (int j=0;j<4;j++){
    int col = n0 + wn + j*16 + lr;
    float bb = bias[col];
    #pragma unroll
    for (int i=0;i<4;i++){
      int rowb = wm + i*16 + quad*4;
      #pragma unroll
      for (int r=0;r<4;r++)
        out[(size_t)(rowb+r)*768 + col] = f2bf(acc[i][j][r] + bb);
    }
  }
}

// ---------------- barrier-free split-key MFMA flash attention, fp32 output ----------------
// blocks 0..7: entity, 16 q rows each; blocks 8..135: word, 16 q rows each.
// All blocks: 4 waves, 4-way key split per block. grid.y = head.
// l (softmax denom) accumulated as a 5th MFMA output with an all-ones B-frag.
__global__ __launch_bounds__(256) void attn_split(
  const unsigned short* __restrict__ Kb,  const unsigned short* __restrict__ VbT,
  const unsigned short* __restrict__ Qw,  const unsigned short* __restrict__ Qwe,
  const unsigned short* __restrict__ Qew, const unsigned short* __restrict__ Qee,
  const float* __restrict__ am,
  float* __restrict__ outw, float* __restrict__ oute)
{
  int bx = blockIdx.x, h = blockIdx.y;
  int tid = threadIdx.x, w = tid>>6, lane = tid&63, quad = lane>>4, lr = lane&15;
  bool isword = bx >= 8;                 // entity blocks first: they have the longest key loop
  int qrb;
  const unsigned short *Qa, *Qb;
  float* outp;
  if (isword){ qrb = (bx-8)*16; Qa=Qw;  Qb=Qwe; outp=outw; }
  else       { qrb = bx*16;     Qa=Qew; Qb=Qee; outp=oute; }
  int kh = w;                            // 4-way key split, one wave each

  // union: in-loop packed-P (per-wave 16*24 u32, wave-private) overlaps the
  // epilogue merge buffer (4*64*24 f32). 24576 B -> 6 blocks/CU LDS cap.
  __shared__ __align__(16) unsigned int shb[4*64*24];
  unsigned int* p32w = shb + w*(16*24);

  const unsigned short* qr = Qa + (size_t)(qrb+lr)*768 + h*64 + quad*8;
  bf16x8 qa0 = ldb(qr), qa1 = ldb(qr + 32);
  qr = Qb + (size_t)(qrb+lr)*768 + h*64 + quad*8;
  bf16x8 qb0 = ldb(qr), qb1 = ldb(qr + 32);

  u16x8 onesu;
  #pragma unroll
  for (int i=0;i<8;i++) onesu[i] = 0x3F80;          // bf16 1.0
  bf16x8 onesf = __builtin_bit_cast(bf16x8, onesu);

  float m_r[4];
  f32x4 o[4], l4;
  #pragma unroll
  for (int r=0;r<4;r++){ m_r[r] = -1e30f; l4[r] = 0.f; }
  #pragma unroll
  for (int n2=0;n2<4;n2++) for (int r=0;r<4;r++) o[n2][r] = 0.f;

  int lo, nw;
  if (isword){
    lo = qrb - 256; if (lo < 0) lo = 0; lo &= ~31;
    int hi = qrb + 272; if (hi > 2048) hi = 2048; hi = (hi + 31) & ~31;
    nw = (hi - lo) >> 5;
  } else { lo = 0; nw = 64; }
  int nc = nw + 4;

  for (int c = kh; c < nc; c += 4){
    bool entp = c >= nw;
    int j0 = entp ? (2048 + (c-nw)*32) : (lo + c*32);

    // K B-frags direct from global (Kb is [key][dim] = B-layout)
    const unsigned short* kp = Kb + (size_t)(j0+lr)*768 + h*64 + quad*8;
    bf16x8 k00 = ldb(kp),          k01 = ldb(kp + 32);
    bf16x8 k10 = ldb(kp + 16*768), k11 = ldb(kp + 16*768 + 32);
    // V B-frags direct from global (VbT is [dim][key] = B-layout for PV)
    const unsigned short* vp = VbT + (size_t)(h*64 + lr)*2176 + j0 + quad*8;
    bf16x8 v0 = ldb(vp), v1 = ldb(vp + 16*2176), v2 = ldb(vp + 32*2176), v3 = ldb(vp + 48*2176);

    bf16x8 qf0 = entp ? qb0 : qa0;
    bf16x8 qf1 = entp ? qb1 : qa1;
    f32x4 s[2];
    {
      f32x4 z0 = {0.f,0.f,0.f,0.f}, z1 = {0.f,0.f,0.f,0.f};
      __builtin_amdgcn_s_setprio(1);
      z0 = __builtin_amdgcn_mfma_f32_16x16x32_bf16(qf0, k00, z0, 0,0,0);
      z0 = __builtin_amdgcn_mfma_f32_16x16x32_bf16(qf1, k01, z0, 0,0,0);
      z1 = __builtin_amdgcn_mfma_f32_16x16x32_bf16(qf0, k10, z1, 0,0,0);
      z1 = __builtin_amdgcn_mfma_f32_16x16x32_bf16(qf1, k11, z1, 0,0,0);
      __builtin_amdgcn_s_setprio(0);
      s[0] = z0; s[1] = z1;
    }

    float sc[2][4];
    bool wband = isword && !entp;
    #pragma unroll
    for (int t=0;t<2;t++){
      int j = j0 + t*16 + lr;
      float amj  = am[j];
      float addl = amj * LOG2E;
      #pragma unroll
      for (int r=0;r<4;r++){
        float sv = s[t][r];
        if (wband){
          sv += (amj != 0.f) ? NEGV : 0.f;                              // float_mask pre-add
          int i = qrb + quad*4 + r;
          bool ok = ((unsigned)(i - j + 256) <= 512u) && (sv != 0.f);   // band & !=0 quirk
          sv = ok ? sv : NEGV;
        }
        sc[t][r] = sv * (LOG2E*0.125f) + addl;
      }
    }

    #pragma unroll
    for (int r=0;r<4;r++){
      float mx = fmaxf(sc[0][r], sc[1][r]);
      mx = fmaxf(mx, __shfl_xor(mx, 1));
      mx = fmaxf(mx, __shfl_xor(mx, 2));
      mx = fmaxf(mx, __shfl_xor(mx, 4));
      mx = fmaxf(mx, __shfl_xor(mx, 8));
      float mn = fmaxf(m_r[r], mx);
      float alpha = exp2f(m_r[r] - mn);
      m_r[r] = mn;
      float p0 = exp2f(sc[0][r]-mn), p1 = exp2f(sc[1][r]-mn);
      unsigned short pb0 = f2bf(p0), pb1 = f2bf(p1);
      p32w[(quad*4+r)*24 + lr] = (unsigned int)pb0 | ((unsigned int)pb1 << 16);
      l4[r] *= alpha;
      #pragma unroll
      for (int n2=0;n2<4;n2++) o[n2][r] *= alpha;
    }

    // P (C-layout) -> A-frag, wave-local LDS round-trip (no barrier needed)
    const unsigned int* pbp = &p32w[lr*24 + (quad&1)*8];
    u32x4 ra = *(const u32x4_a*)pbp;
    u32x4 rb = *(const u32x4_a*)(pbp + 4);
    unsigned int pf32[4];
    if (quad < 2){
      pf32[0] = (ra[0]&0xFFFFu) | (ra[1]<<16);
      pf32[1] = (ra[2]&0xFFFFu) | (ra[3]<<16);
      pf32[2] = (rb[0]&0xFFFFu) | (rb[1]<<16);
      pf32[3] = (rb[2]&0xFFFFu) | (rb[3]<<16);
    } else {
      pf32[0] = (ra[0]>>16) | (ra[1]&0xFFFF0000u);
      pf32[1] = (ra[2]>>16) | (ra[3]&0xFFFF0000u);
      pf32[2] = (rb[0]>>16) | (rb[1]&0xFFFF0000u);
      pf32[3] = (rb[2]>>16) | (rb[3]&0xFFFF0000u);
    }
    u32x4 pfv = {pf32[0], pf32[1], pf32[2], pf32[3]};
    bf16x8 pf = __builtin_bit_cast(bf16x8, pfv);

    __builtin_amdgcn_s_setprio(1);
    o[0] = __builtin_amdgcn_mfma_f32_16x16x32_bf16(pf, v0, o[0], 0,0,0);
    o[1] = __builtin_amdgcn_mfma_f32_16x16x32_bf16(pf, v1, o[1], 0,0,0);
    o[2] = __builtin_amdgcn_mfma_f32_16x16x32_bf16(pf, v2, o[2], 0,0,0);
    o[3] = __builtin_amdgcn_mfma_f32_16x16x32_bf16(pf, v3, o[3], 0,0,0);
    l4   = __builtin_amdgcn_mfma_f32_16x16x32_bf16(pf, onesf, l4, 0,0,0);   // row sums
    __builtin_amdgcn_s_setprio(0);
  }

  // ---- cross-wave merge ----
  __syncthreads();          // p32 region is being reused as merge buffer below
  {
    float* my = (float*)shb + ((size_t)w*64 + lane)*24;
    #pragma unroll
    for (int r=0;r<4;r++){ my[r] = m_r[r]; my[4+r] = l4[r]; }
    #pragma unroll
    for (int n2=0;n2<4;n2++)
      #pragma unroll
      for (int r=0;r<4;r++) my[8+n2*4+r] = o[n2][r];
  }
  __syncthreads();
  // each wave merges and stores its own 16-col output slice (n2 == w)
  {
    f32x4 oo = o[w];
    float mm[4], ll[4];
    #pragma unroll
    for (int r=0;r<4;r++){ mm[r] = m_r[r]; ll[r] = l4[r]; }
    #pragma unroll
    for (int p=0;p<4;p++){
      if (p == w) continue;
      const float* pr = (float*)shb + ((size_t)p*64 + lane)*24;
      #pragma unroll
      for (int r=0;r<4;r++){
        float m2 = pr[r], l2 = pr[4+r], o2 = pr[8+w*4+r];
        float M  = fmaxf(mm[r], m2);
        float e1 = exp2f(mm[r]-M), e2 = exp2f(m2-M);
        mm[r] = M;
        ll[r] = ll[r]*e1 + l2*e2;
        oo[r] = oo[r]*e1 + o2*e2;
      }
    }
    #pragma unroll
    for (int r=0;r<4;r++){
      int row = qrb + quad*4 + r;
      outp[(size_t)row*768 + h*64 + w*16 + lr] = oo[r] / ll[r];
    }
  }
}

extern "C" void kernel_launch(void* const* d_in, const int* in_sizes, int n_in,
                              void* d_out, int out_size, void* d_ws, size_t ws_size,
                              hipStream_t stream) {
  const float* word  = (const float*)d_in[0];
  const float* ent   = (const float*)d_in[1];
  const float* am    = (const float*)d_in[2];
  const float* q_w   = (const float*)d_in[3];
  const float* q_b   = (const float*)d_in[4];
  const float* k_w   = (const float*)d_in[5];
  const float* k_b   = (const float*)d_in[6];
  const float* v_w   = (const float*)d_in[7];
  const float* v_b   = (const float*)d_in[8];
  const float* w2e_w = (const float*)d_in[9];
  const float* w2e_b = (const float*)d_in[10];
  const float* e2w_w = (const float*)d_in[11];
  const float* e2w_b = (const float*)d_in[12];
  const float* e2e_w = (const float*)d_in[13];
  const float* e2e_b = (const float*)d_in[14];

  unsigned short* ws  = (unsigned short*)d_ws;
  unsigned short* wT  = ws;                       // 6*768*768 bf16
  unsigned short* Kb  = wT  + (size_t)6*589824;   // 2176*768
  unsigned short* Vb  = Kb  + (size_t)2176*768;
  unsigned short* Qw  = Vb  + (size_t)2176*768;   // 2048*768
  unsigned short* Qwe = Qw  + (size_t)2048*768;
  unsigned short* Qew = Qwe + (size_t)2048*768;   // 128*768
  unsigned short* Qee = Qew + (size_t)128*768;
  unsigned short* VbT = Qee + (size_t)128*768;    // 768*2176

  float* outw = (float*)d_out;                    // fp32 output
  float* oute = outw + (size_t)2048*768;

  hipLaunchKernelGGL(transpose6, dim3(24,24,6), dim3(32,8), 0, stream,
                     k_w, v_w, q_w, w2e_w, e2w_w, e2e_w, wT);
  hipLaunchKernelGGL(gemm_proj, dim3(68,6), dim3(256), 0, stream,
                     word, ent, wT, k_b, v_b, q_b, w2e_b, e2w_b, e2e_b,
                     Kb, Vb, Qw, Qwe, Qew, Qee);
  hipLaunchKernelGGL(transpose_v, dim3(68,24), dim3(32,8), 0, stream, Vb, VbT);
  hipLaunchKernelGGL(attn_split, dim3(136,12), dim3(256), 0, stream,
                     Kb, VbT, Qw, Qwe, Qew, Qee, am, outw, oute);
}

// Round 2
// 192.266 us; speedup vs baseline: 1.0778x; 1.0778x over previous
//
#include <hip/hip_runtime.h>

typedef __bf16 bf16x8 __attribute__((ext_vector_type(8)));
typedef unsigned short u16x8 __attribute__((ext_vector_type(8)));
typedef u16x8 u16x8_a __attribute__((may_alias));
typedef unsigned int u32x4 __attribute__((ext_vector_type(4)));
typedef u32x4 u32x4_a __attribute__((may_alias));
typedef float f32x4 __attribute__((ext_vector_type(4)));

#define LOG2E 1.4426950408889634f
#define NEGV  -10000.0f

__device__ __forceinline__ float bf2f(unsigned short u){
  union{unsigned int i; float f;} x; x.i = ((unsigned int)u)<<16; return x.f;
}
__device__ __forceinline__ unsigned short f2bf(float f){
  union{float f; unsigned int i;} x; x.f=f;
  unsigned int i = x.i;
  return (unsigned short)((i + 0x7FFFu + ((i>>16)&1u)) >> 16);
}
__device__ __forceinline__ u16x8 cvt8(float4 a, float4 b){
  u16x8 r;
  r[0]=f2bf(a.x); r[1]=f2bf(a.y); r[2]=f2bf(a.z); r[3]=f2bf(a.w);
  r[4]=f2bf(b.x); r[5]=f2bf(b.y); r[6]=f2bf(b.z); r[7]=f2bf(b.w);
  return r;
}
__device__ __forceinline__ bf16x8 ldb(const unsigned short* p){
  return __builtin_bit_cast(bf16x8, *(const u16x8_a*)p);
}

// ---------------- weight transpose+cast: wT[g][n][k] = bf16(w[g][k][n]), 768x768 ----------------
__global__ __launch_bounds__(256) void transpose6(
    const float* __restrict__ w0, const float* __restrict__ w1,
    const float* __restrict__ w2, const float* __restrict__ w3,
    const float* __restrict__ w4, const float* __restrict__ w5,
    unsigned short* __restrict__ outT)
{
  const float* src;
  switch (blockIdx.z){
    case 0: src = w0; break; case 1: src = w1; break; case 2: src = w2; break;
    case 3: src = w3; break; case 4: src = w4; break; default: src = w5; break;
  }
  unsigned short* dst = outT + (size_t)blockIdx.z * 589824;
  __shared__ float tile[32][33];
  int tx = threadIdx.x, ty = threadIdx.y;
  int x0 = blockIdx.x*32, y0 = blockIdx.y*32;
  #pragma unroll
  for (int i=0;i<32;i+=8) tile[ty+i][tx] = src[(size_t)(y0+ty+i)*768 + x0+tx];
  __syncthreads();
  #pragma unroll
  for (int i=0;i<32;i+=8) dst[(size_t)(x0+ty+i)*768 + y0+tx] = f2bf(tile[tx][ty+i]);
}

// ---------------- V transpose: VbT[d][key] = Vb[key][d] (bf16, 2176x768 -> 768x2176) ----
__global__ __launch_bounds__(256) void transpose_v(
    const unsigned short* __restrict__ Vb, unsigned short* __restrict__ VbT)
{
  __shared__ unsigned short t[32][33];
  int tx = threadIdx.x, ty = threadIdx.y;
  int x0 = blockIdx.x*32;   // key
  int y0 = blockIdx.y*32;   // dim
  #pragma unroll
  for (int i=0;i<32;i+=8) t[ty+i][tx] = Vb[(size_t)(x0+ty+i)*768 + y0+tx];
  __syncthreads();
  #pragma unroll
  for (int i=0;i<32;i+=8) VbT[(size_t)(y0+ty+i)*2176 + x0+tx] = t[tx][ty+i];
}

// ---------------- batched projection GEMM: out = bf16(A fp32) @ wT(bf16) + bias(fp32) ----------------
__global__ __launch_bounds__(256) void gemm_proj(
    const float* __restrict__ word, const float* __restrict__ ent,
    const unsigned short* __restrict__ wT,
    const float* __restrict__ bK, const float* __restrict__ bV,
    const float* __restrict__ bQ, const float* __restrict__ bWE,
    const float* __restrict__ bEW, const float* __restrict__ bEE,
    unsigned short* __restrict__ oK, unsigned short* __restrict__ oV,
    unsigned short* __restrict__ oQ, unsigned short* __restrict__ oWE,
    unsigned short* __restrict__ oEW, unsigned short* __restrict__ oEE)
{
  int mt = blockIdx.x, ntile = blockIdx.y;
  int g, mg;
  if      (mt < 17){ g=0; mg=mt;    }
  else if (mt < 34){ g=1; mg=mt-17; }
  else if (mt < 50){ g=2; mg=mt-34; }
  else if (mt < 66){ g=3; mg=mt-50; }
  else if (mt < 67){ g=4; mg=0;     }
  else             { g=5; mg=0;     }
  int m0 = mg*128;
  const float* A;
  if (g<=1)      A = (mg<16) ? (word + (size_t)m0*768) : ent;
  else if (g<=3) A = word + (size_t)m0*768;
  else           A = ent;
  const unsigned short* B = wT + (size_t)g*589824;
  const float* bias; unsigned short* out;
  switch (g){
    case 0: bias=bK;  out=oK;  break;
    case 1: bias=bV;  out=oV;  break;
    case 2: bias=bQ;  out=oQ;  break;
    case 3: bias=bWE; out=oWE; break;
    case 4: bias=bEW; out=oEW; break;
    default:bias=bEE; out=oEE; break;
  }
  out += (size_t)m0*768;
  int n0 = ntile*128;

  __shared__ __align__(16) unsigned short a_s[128*32];
  __shared__ __align__(16) unsigned short b_s[128*32];

  int tid  = threadIdx.x;
  int w    = tid>>6, lane = tid&63, quad = lane>>4, lr = lane&15;
  int wm   = (w&1)*64, wn = (w>>1)*64;

  f32x4 acc[4][4];
  #pragma unroll
  for (int i=0;i<4;i++) for (int j=0;j<4;j++) for (int r=0;r<4;r++) acc[i][j][r]=0.f;

  int ar = tid>>1;
  int ak = (tid&1)*16;
  const float* Arow = A + (size_t)ar*768 + ak;
  const unsigned short* Brow = B + (size_t)(n0+ar)*768 + ak;

  for (int k0=0; k0<768; k0+=32){
    float4 af0 = *(const float4*)(Arow + k0);
    float4 af1 = *(const float4*)(Arow + k0 + 4);
    float4 af2 = *(const float4*)(Arow + k0 + 8);
    float4 af3 = *(const float4*)(Arow + k0 + 12);
    u16x8 av0 = cvt8(af0, af1);
    u16x8 av1 = cvt8(af2, af3);
    u16x8 bv0 = *(const u16x8_a*)(Brow + k0);
    u16x8 bv1 = *(const u16x8_a*)(Brow + k0 + 8);
    __syncthreads();
    *(u16x8_a*)(a_s + ar*32 + ak)     = av0;
    *(u16x8_a*)(a_s + ar*32 + ak + 8) = av1;
    *(u16x8_a*)(b_s + ar*32 + ak)     = bv0;
    *(u16x8_a*)(b_s + ar*32 + ak + 8) = bv1;
    __syncthreads();
    bf16x8 af[4], bfr[4];
    #pragma unroll
    for (int i=0;i<4;i++) af[i]  = ldb(a_s + (wm+i*16+lr)*32 + quad*8);
    #pragma unroll
    for (int i=0;i<4;i++) bfr[i] = ldb(b_s + (wn+i*16+lr)*32 + quad*8);
    #pragma unroll
    for (int i=0;i<4;i++)
      #pragma unroll
      for (int j=0;j<4;j++)
        acc[i][j] = __builtin_amdgcn_mfma_f32_16x16x32_bf16(af[i], bfr[j], acc[i][j], 0,0,0);
  }
  #pragma unroll
  for (int j=0;j<4;j++){
    int col = n0 + wn + j*16 + lr;
    float bb = bias[col];
    #pragma unroll
    for (int i=0;i<4;i++){
      int rowb = wm + i*16 + quad*4;
      #pragma unroll
      for (int r=0;r<4;r++)
        out[(size_t)(rowb+r)*768 + col] = f2bf(acc[i][j][r] + bb);
    }
  }
}

// ---------------- barrier-free split-key MFMA flash attention, fp32 output ----------------
// grid (80,12), XCD-swizzled. bx 0..63: word, 32 q rows (2 groups x 16, key-split 2 ways).
// bx 64..79: entity, 16 q rows, keys split 2 ways ACROSS blocks (half) and 4 ways across
// waves; partial (m,l,o) written to workspace, merged by merge_ent.
// l (softmax denom) accumulated as a 5th MFMA with an all-ones B-frag.
__global__ __launch_bounds__(256) void attn_split(
  const unsigned short* __restrict__ Kb,  const unsigned short* __restrict__ VbT,
  const unsigned short* __restrict__ Qw,  const unsigned short* __restrict__ Qwe,
  const unsigned short* __restrict__ Qew, const unsigned short* __restrict__ Qee,
  const float* __restrict__ am,
  float* __restrict__ outw, float* __restrict__ pO, float* __restrict__ pML)
{
  // XCD-aware swizzle: 960 blocks, 8 XCDs -> each XCD gets 120 consecutive work ids
  // (head-major) => per-XCD K/V working set ~1.1 MB, fits 4 MB L2.
  int lin = blockIdx.x + 80*blockIdx.y;
  int wid = (lin & 7)*120 + (lin >> 3);
  int bx = wid % 80;
  int h  = wid / 80;

  int tid = threadIdx.x, w = tid>>6, lane = tid&63, quad = lane>>4, lr = lane&15;
  bool isword = bx < 64;
  int qrb, kh, nsplit, eg=0, ehalf=0;
  const unsigned short *Qa, *Qb;
  if (isword){ qrb = bx*32 + (w>>1)*16; kh = w&1; nsplit = 2; Qa=Qw;  Qb=Qwe; }
  else       { int e = bx-64; eg = e>>1; ehalf = e&1;
               qrb = eg*16;             kh = w;   nsplit = 4; Qa=Qew; Qb=Qee; }
  int hofs = h*64;

  __shared__ __align__(16) unsigned int p32[4][16*24];  // packed P, stride 24 (2-way banks)
  __shared__ float mrg[4][64][24];                      // merge buffer (epilogue only)

  const unsigned short* qr = Qa + (size_t)(qrb+lr)*768 + hofs + quad*8;
  bf16x8 qa0 = ldb(qr), qa1 = ldb(qr + 32);
  qr = Qb + (size_t)(qrb+lr)*768 + hofs + quad*8;
  bf16x8 qb0 = ldb(qr), qb1 = ldb(qr + 32);

  u16x8 onesu;
  #pragma unroll
  for (int i=0;i<8;i++) onesu[i] = 0x3F80;          // bf16 1.0
  bf16x8 onesf = __builtin_bit_cast(bf16x8, onesu);

  unsigned int* p32w = &p32[w][0];

  float m_r[4];
  f32x4 o[4], l4;
  #pragma unroll
  for (int r=0;r<4;r++){ m_r[r] = -1e30f; l4[r] = 0.f; }
  #pragma unroll
  for (int n2=0;n2<4;n2++) for (int r=0;r<4;r++) o[n2][r] = 0.f;

  int lo, nw, start, end, step;
  if (isword){
    lo = qrb - 256; if (lo < 0) lo = 0; lo &= ~31;        // padded keys are band-masked
    int hi = qrb + 272; if (hi > 2048) hi = 2048; hi = (hi + 31) & ~31;
    nw = (hi - lo) >> 5;
    start = kh; end = nw + 4; step = 2;
  } else {
    lo = 0; nw = 64;
    start = ehalf*34 + kh; end = ehalf*34 + 34; step = 4;  // 68 total chunks, block-split 2 ways
  }

#define LOADK(K0,K1,K2,K3,CC) do { \
    bool entp_ = (CC) >= nw; \
    int j0_ = entp_ ? (2048 + ((CC)-nw)*32) : (lo + (CC)*32); \
    const unsigned short* kp_ = Kb + (size_t)(j0_+lr)*768 + hofs + quad*8; \
    K0 = ldb(kp_); K1 = ldb(kp_+32); K2 = ldb(kp_+16*768); K3 = ldb(kp_+16*768+32); \
  } while(0)

#define COMPUTE(K0,K1,K2,K3,CC) do { \
    bool entp = (CC) >= nw; \
    int j0 = entp ? (2048 + ((CC)-nw)*32) : (lo + (CC)*32); \
    const unsigned short* vp = VbT + (size_t)(hofs + lr)*2176 + j0 + quad*8; \
    bf16x8 v0 = ldb(vp), v1 = ldb(vp + 16*2176), v2 = ldb(vp + 32*2176), v3 = ldb(vp + 48*2176); \
    bf16x8 qf0 = entp ? qb0 : qa0; \
    bf16x8 qf1 = entp ? qb1 : qa1; \
    f32x4 s[2]; \
    { \
      f32x4 z0 = {0.f,0.f,0.f,0.f}, z1 = {0.f,0.f,0.f,0.f}; \
      __builtin_amdgcn_s_setprio(1); \
      z0 = __builtin_amdgcn_mfma_f32_16x16x32_bf16(qf0, K0, z0, 0,0,0); \
      z0 = __builtin_amdgcn_mfma_f32_16x16x32_bf16(qf1, K1, z0, 0,0,0); \
      z1 = __builtin_amdgcn_mfma_f32_16x16x32_bf16(qf0, K2, z1, 0,0,0); \
      z1 = __builtin_amdgcn_mfma_f32_16x16x32_bf16(qf1, K3, z1, 0,0,0); \
      __builtin_amdgcn_s_setprio(0); \
      s[0] = z0; s[1] = z1; \
    } \
    float sc[2][4]; \
    bool wband = isword && !entp; \
    _Pragma("unroll") \
    for (int t=0;t<2;t++){ \
      int j = j0 + t*16 + lr; \
      float amj  = am[j]; \
      float addl = amj * LOG2E; \
      _Pragma("unroll") \
      for (int r=0;r<4;r++){ \
        float sv = s[t][r]; \
        if (wband){ \
          sv += (amj != 0.f) ? NEGV : 0.f; \
          int i = qrb + quad*4 + r; \
          bool ok = ((unsigned)(i - j + 256) <= 512u) && (sv != 0.f); \
          sv = ok ? sv : NEGV; \
        } \
        sc[t][r] = sv * (LOG2E*0.125f) + addl; \
      } \
    } \
    _Pragma("unroll") \
    for (int r=0;r<4;r++){ \
      float mx = fmaxf(sc[0][r], sc[1][r]); \
      mx = fmaxf(mx, __shfl_xor(mx, 1)); \
      mx = fmaxf(mx, __shfl_xor(mx, 2)); \
      mx = fmaxf(mx, __shfl_xor(mx, 4)); \
      mx = fmaxf(mx, __shfl_xor(mx, 8)); \
      float mn = fmaxf(m_r[r], mx); \
      float alpha = exp2f(m_r[r] - mn); \
      m_r[r] = mn; \
      float p0 = exp2f(sc[0][r]-mn), p1 = exp2f(sc[1][r]-mn); \
      unsigned short pb0 = f2bf(p0), pb1 = f2bf(p1); \
      p32w[(quad*4+r)*24 + lr] = (unsigned int)pb0 | ((unsigned int)pb1 << 16); \
      l4[r] *= alpha; \
      _Pragma("unroll") \
      for (int n2=0;n2<4;n2++) o[n2][r] *= alpha; \
    } \
    const unsigned int* pbp = &p32w[lr*24 + (quad&1)*8]; \
    u32x4 ra = *(const u32x4_a*)pbp; \
    u32x4 rb = *(const u32x4_a*)(pbp + 4); \
    unsigned int pf32[4]; \
    if (quad < 2){ \
      pf32[0] = (ra[0]&0xFFFFu) | (ra[1]<<16); \
      pf32[1] = (ra[2]&0xFFFFu) | (ra[3]<<16); \
      pf32[2] = (rb[0]&0xFFFFu) | (rb[1]<<16); \
      pf32[3] = (rb[2]&0xFFFFu) | (rb[3]<<16); \
    } else { \
      pf32[0] = (ra[0]>>16) | (ra[1]&0xFFFF0000u); \
      pf32[1] = (ra[2]>>16) | (ra[3]&0xFFFF0000u); \
      pf32[2] = (rb[0]>>16) | (rb[1]&0xFFFF0000u); \
      pf32[3] = (rb[2]>>16) | (rb[3]&0xFFFF0000u); \
    } \
    u32x4 pfv = {pf32[0], pf32[1], pf32[2], pf32[3]}; \
    bf16x8 pf = __builtin_bit_cast(bf16x8, pfv); \
    __builtin_amdgcn_s_setprio(1); \
    o[0] = __builtin_amdgcn_mfma_f32_16x16x32_bf16(pf, v0, o[0], 0,0,0); \
    o[1] = __builtin_amdgcn_mfma_f32_16x16x32_bf16(pf, v1, o[1], 0,0,0); \
    o[2] = __builtin_amdgcn_mfma_f32_16x16x32_bf16(pf, v2, o[2], 0,0,0); \
    o[3] = __builtin_amdgcn_mfma_f32_16x16x32_bf16(pf, v3, o[3], 0,0,0); \
    l4   = __builtin_amdgcn_mfma_f32_16x16x32_bf16(pf, onesf, l4, 0,0,0); \
    __builtin_amdgcn_s_setprio(0); \
  } while(0)

  // K double-buffered prefetch: issue next chunk's K loads before computing current.
  {
    int c = start;
    bf16x8 kA0,kA1,kA2,kA3, kB0,kB1,kB2,kB3;
    if (c < end) LOADK(kA0,kA1,kA2,kA3,c);
    while (c < end) {
      int c1 = c + step;
      bool hb = c1 < end;
      if (hb) LOADK(kB0,kB1,kB2,kB3,c1);
      COMPUTE(kA0,kA1,kA2,kA3,c);
      if (!hb) break;
      int c2 = c1 + step;
      bool ha = c2 < end;
      if (ha) LOADK(kA0,kA1,kA2,kA3,c2);
      COMPUTE(kB0,kB1,kB2,kB3,c1);
      c = c2;
    }
  }
#undef LOADK
#undef COMPUTE

  // ---- cross-wave merge (single barrier) ----
  {
    float* my = &mrg[w][lane][0];
    #pragma unroll
    for (int r=0;r<4;r++){ my[r] = m_r[r]; my[4+r] = l4[r]; }
    #pragma unroll
    for (int n2=0;n2<4;n2++)
      #pragma unroll
      for (int r=0;r<4;r++) my[8+n2*4+r] = o[n2][r];
  }
  __syncthreads();
  if (kh == 0){
    for (int p=1; p<nsplit; p++){
      const float* pr = &mrg[w+p][lane][0];
      #pragma unroll
      for (int r=0;r<4;r++){
        float m2 = pr[r], l2 = pr[4+r];
        float M  = fmaxf(m_r[r], m2);
        float e1 = exp2f(m_r[r]-M), e2 = exp2f(m2-M);
        m_r[r] = M;
        l4[r] = l4[r]*e1 + l2*e2;
        #pragma unroll
        for (int n2=0;n2<4;n2++)
          o[n2][r] = o[n2][r]*e1 + pr[8+n2*4+r]*e2;
      }
    }
    if (isword){
      #pragma unroll
      for (int n2=0;n2<4;n2++)
        #pragma unroll
        for (int r=0;r<4;r++){
          int row = qrb + quad*4 + r;
          outw[(size_t)row*768 + hofs + n2*16 + lr] = o[n2][r] / l4[r];
        }
    } else {
      int idx = (eg*12 + h)*2 + ehalf;
      float* po = pO + (size_t)idx*1024;
      #pragma unroll
      for (int n2=0;n2<4;n2++)
        #pragma unroll
        for (int r=0;r<4;r++)
          po[(quad*4+r)*64 + n2*16 + lr] = o[n2][r];
      if (lr == 0){
        float* pml = pML + (size_t)idx*32;
        #pragma unroll
        for (int r=0;r<4;r++){
          pml[(quad*4+r)*2]     = m_r[r];
          pml[(quad*4+r)*2 + 1] = l4[r];
        }
      }
    }
  }
}

// ---------------- entity cross-block merge: 2 key-halves -> final output ----------------
__global__ __launch_bounds__(256) void merge_ent(
    const float* __restrict__ pO, const float* __restrict__ pML,
    float* __restrict__ oute)
{
  int b = blockIdx.x;            // 0..95 = eg*12 + h
  int g = b/12, h = b%12;
  int tid = threadIdx.x;
  int row = tid>>4, cg = tid&15;
  int i0 = b*2, i1 = b*2+1;
  float m0 = pML[(size_t)i0*32 + row*2], l0 = pML[(size_t)i0*32 + row*2 + 1];
  float m1 = pML[(size_t)i1*32 + row*2], l1 = pML[(size_t)i1*32 + row*2 + 1];
  float M  = fmaxf(m0, m1);
  float e0 = exp2f(m0-M), e1 = exp2f(m1-M);
  float rl = 1.f/(l0*e0 + l1*e1);
  float4 a = *(const float4*)(pO + (size_t)i0*1024 + row*64 + cg*4);
  float4 c = *(const float4*)(pO + (size_t)i1*1024 + row*64 + cg*4);
  float4 o;
  o.x = (a.x*e0 + c.x*e1)*rl;
  o.y = (a.y*e0 + c.y*e1)*rl;
  o.z = (a.z*e0 + c.z*e1)*rl;
  o.w = (a.w*e0 + c.w*e1)*rl;
  *(float4*)(oute + (size_t)(g*16+row)*768 + h*64 + cg*4) = o;
}

extern "C" void kernel_launch(void* const* d_in, const int* in_sizes, int n_in,
                              void* d_out, int out_size, void* d_ws, size_t ws_size,
                              hipStream_t stream) {
  const float* word  = (const float*)d_in[0];
  const float* ent   = (const float*)d_in[1];
  const float* am    = (const float*)d_in[2];
  const float* q_w   = (const float*)d_in[3];
  const float* q_b   = (const float*)d_in[4];
  const float* k_w   = (const float*)d_in[5];
  const float* k_b   = (const float*)d_in[6];
  const float* v_w   = (const float*)d_in[7];
  const float* v_b   = (const float*)d_in[8];
  const float* w2e_w = (const float*)d_in[9];
  const float* w2e_b = (const float*)d_in[10];
  const float* e2w_w = (const float*)d_in[11];
  const float* e2w_b = (const float*)d_in[12];
  const float* e2e_w = (const float*)d_in[13];
  const float* e2e_b = (const float*)d_in[14];

  unsigned short* ws  = (unsigned short*)d_ws;
  unsigned short* wT  = ws;                       // 6*768*768 bf16 (dead after gemm_proj)
  unsigned short* Kb  = wT  + (size_t)6*589824;   // 2176*768
  unsigned short* Vb  = Kb  + (size_t)2176*768;
  unsigned short* Qw  = Vb  + (size_t)2176*768;   // 2048*768
  unsigned short* Qwe = Qw  + (size_t)2048*768;
  unsigned short* Qew = Qwe + (size_t)2048*768;   // 128*768
  unsigned short* Qee = Qew + (size_t)128*768;
  unsigned short* VbT = Qee + (size_t)128*768;    // 768*2176

  // entity partials live in the dead wT region during attention
  float* pO  = (float*)wT;                        // 192 * 16*64 f32 = 786 KB
  float* pML = pO + (size_t)192*1024;             // 192 * 16*2  f32

  float* outw = (float*)d_out;                    // fp32 output
  float* oute = outw + (size_t)2048*768;

  hipLaunchKernelGGL(transpose6, dim3(24,24,6), dim3(32,8), 0, stream,
                     k_w, v_w, q_w, w2e_w, e2w_w, e2e_w, wT);
  hipLaunchKernelGGL(gemm_proj, dim3(68,6), dim3(256), 0, stream,
                     word, ent, wT, k_b, v_b, q_b, w2e_b, e2w_b, e2e_b,
                     Kb, Vb, Qw, Qwe, Qew, Qee);
  hipLaunchKernelGGL(transpose_v, dim3(68,24), dim3(32,8), 0, stream, Vb, VbT);
  hipLaunchKernelGGL(attn_split, dim3(80,12), dim3(256), 0, stream,
                     Kb, VbT, Qw, Qwe, Qew, Qee, am, outw, pO, pML);
  hipLaunchKernelGGL(merge_ent, dim3(96), dim3(256), 0, stream,
                     pO, pML, oute);
}

// Round 3
// 180.602 us; speedup vs baseline: 1.1474x; 1.0646x over previous
//
#include <hip/hip_runtime.h>

typedef __bf16 bf16x8 __attribute__((ext_vector_type(8)));
typedef unsigned short u16x8 __attribute__((ext_vector_type(8)));
typedef u16x8 u16x8_a __attribute__((may_alias));
typedef unsigned int u32x2 __attribute__((ext_vector_type(2)));
typedef u32x2 u32x2_a __attribute__((may_alias));
typedef unsigned int u32x4 __attribute__((ext_vector_type(4)));
typedef u32x4 u32x4_a __attribute__((may_alias));
typedef float f32x4 __attribute__((ext_vector_type(4)));

#define LOG2E 1.4426950408889634f
#define NEGV  -10000.0f

__device__ __forceinline__ unsigned short f2bf(float f){
  union{float f; unsigned int i;} x; x.f=f;
  unsigned int i = x.i;
  return (unsigned short)((i + 0x7FFFu + ((i>>16)&1u)) >> 16);
}
__device__ __forceinline__ u16x8 cvt8(float4 a, float4 b){
  u16x8 r;
  r[0]=f2bf(a.x); r[1]=f2bf(a.y); r[2]=f2bf(a.z); r[3]=f2bf(a.w);
  r[4]=f2bf(b.x); r[5]=f2bf(b.y); r[6]=f2bf(b.z); r[7]=f2bf(b.w);
  return r;
}
__device__ __forceinline__ bf16x8 ldb(const unsigned short* p){
  return __builtin_bit_cast(bf16x8, *(const u16x8_a*)p);
}

// ---------------- A cast: Abf[concat row][k] = bf16(concat(word,ent)), 2176x768 ----------------
__global__ __launch_bounds__(256) void cast_a(
    const float* __restrict__ word, const float* __restrict__ ent,
    unsigned short* __restrict__ Abf)
{
  size_t e = ((size_t)blockIdx.x*256 + threadIdx.x)*8;   // 2176*768/8/256 = 816 blocks exact
  const size_t WE = (size_t)2048*768;
  const float* s = (e < WE) ? (word + e) : (ent + (e - WE));
  float4 a = *(const float4*)s;
  float4 b = *(const float4*)(s+4);
  *(u16x8_a*)(Abf + e) = cvt8(a,b);
}

// ---------------- weight transpose+cast: wT[g][n][k] = bf16(w[g][k][n]), 768x768 ----------------
__global__ __launch_bounds__(256) void transpose6(
    const float* __restrict__ w0, const float* __restrict__ w1,
    const float* __restrict__ w2, const float* __restrict__ w3,
    const float* __restrict__ w4, const float* __restrict__ w5,
    unsigned short* __restrict__ outT)
{
  const float* src;
  switch (blockIdx.z){
    case 0: src = w0; break; case 1: src = w1; break; case 2: src = w2; break;
    case 3: src = w3; break; case 4: src = w4; break; default: src = w5; break;
  }
  unsigned short* dst = outT + (size_t)blockIdx.z * 589824;
  __shared__ float tile[32][33];
  int tx = threadIdx.x, ty = threadIdx.y;
  int x0 = blockIdx.x*32, y0 = blockIdx.y*32;
  #pragma unroll
  for (int i=0;i<32;i+=8) tile[ty+i][tx] = src[(size_t)(y0+ty+i)*768 + x0+tx];
  __syncthreads();
  #pragma unroll
  for (int i=0;i<32;i+=8) dst[(size_t)(x0+ty+i)*768 + y0+tx] = f2bf(tile[tx][ty+i]);
}

// ---------------- V transpose: VbT[d][key] = Vb[key][d] (bf16, 2176x768 -> 768x2176) ----
__global__ __launch_bounds__(256) void transpose_v(
    const unsigned short* __restrict__ Vb, unsigned short* __restrict__ VbT)
{
  __shared__ unsigned short t[32][33];
  int tx = threadIdx.x, ty = threadIdx.y;
  int x0 = blockIdx.x*32;   // key
  int y0 = blockIdx.y*32;   // dim
  #pragma unroll
  for (int i=0;i<32;i+=8) t[ty+i][tx] = Vb[(size_t)(x0+ty+i)*768 + y0+tx];
  __syncthreads();
  #pragma unroll
  for (int i=0;i<32;i+=8) VbT[(size_t)(y0+ty+i)*2176 + x0+tx] = t[tx][ty+i];
}

// ---------------- batched projection GEMM: out = Abf(bf16) @ wT(bf16) + bias(fp32) ----------------
// 64x128 tiles, grid (136,6) = 816 blocks (3.2/CU) for latency hiding.
__global__ __launch_bounds__(256) void gemm_proj(
    const unsigned short* __restrict__ Abf,
    const unsigned short* __restrict__ wT,
    const float* __restrict__ bK, const float* __restrict__ bV,
    const float* __restrict__ bQ, const float* __restrict__ bWE,
    const float* __restrict__ bEW, const float* __restrict__ bEE,
    unsigned short* __restrict__ oK, unsigned short* __restrict__ oV,
    unsigned short* __restrict__ oQ, unsigned short* __restrict__ oWE,
    unsigned short* __restrict__ oEW, unsigned short* __restrict__ oEE)
{
  int mt = blockIdx.x, ntile = blockIdx.y;
  int g, mg;
  if      (mt <  34){ g=0; mg=mt;     }
  else if (mt <  68){ g=1; mg=mt-34;  }
  else if (mt < 100){ g=2; mg=mt-68;  }
  else if (mt < 132){ g=3; mg=mt-100; }
  else if (mt < 134){ g=4; mg=mt-132; }
  else              { g=5; mg=mt-134; }
  int m0 = mg*64;
  const unsigned short* A = Abf + (size_t)((g>=4 ? 2048 : 0) + m0)*768;
  const unsigned short* B = wT + (size_t)g*589824;
  const float* bias; unsigned short* out;
  switch (g){
    case 0: bias=bK;  out=oK;  break;
    case 1: bias=bV;  out=oV;  break;
    case 2: bias=bQ;  out=oQ;  break;
    case 3: bias=bWE; out=oWE; break;
    case 4: bias=bEW; out=oEW; break;
    default:bias=bEE; out=oEE; break;
  }
  out += (size_t)m0*768;
  int n0 = ntile*128;

  __shared__ __align__(16) unsigned short a_s[64*32];
  __shared__ __align__(16) unsigned short b_s[128*32];

  int tid  = threadIdx.x;
  int w    = tid>>6, lane = tid&63, quad = lane>>4, lr = lane&15;
  int wm   = (w&1)*32, wn = (w>>1)*64;

  f32x4 acc[2][4];
  #pragma unroll
  for (int i=0;i<2;i++) for (int j=0;j<4;j++) for (int r=0;r<4;r++) acc[i][j][r]=0.f;

  int ar  = tid>>1;             // B staging: 128 rows
  int ak2 = (tid&1)*16;
  int aar = tid>>2;             // A staging: 64 rows
  int aak = (tid&3)*8;
  const unsigned short* Arow = A + (size_t)aar*768 + aak;
  const unsigned short* Brow = B + (size_t)(n0+ar)*768 + ak2;

  for (int k0=0; k0<768; k0+=32){
    u16x8 av  = *(const u16x8_a*)(Arow + k0);
    u16x8 bv0 = *(const u16x8_a*)(Brow + k0);
    u16x8 bv1 = *(const u16x8_a*)(Brow + k0 + 8);
    __syncthreads();
    *(u16x8_a*)(a_s + aar*32 + aak)    = av;
    *(u16x8_a*)(b_s + ar*32 + ak2)     = bv0;
    *(u16x8_a*)(b_s + ar*32 + ak2 + 8) = bv1;
    __syncthreads();
    bf16x8 af[2], bfr[4];
    #pragma unroll
    for (int i=0;i<2;i++) af[i]  = ldb(a_s + (wm+i*16+lr)*32 + quad*8);
    #pragma unroll
    for (int j=0;j<4;j++) bfr[j] = ldb(b_s + (wn+j*16+lr)*32 + quad*8);
    #pragma unroll
    for (int i=0;i<2;i++)
      #pragma unroll
      for (int j=0;j<4;j++)
        acc[i][j] = __builtin_amdgcn_mfma_f32_16x16x32_bf16(af[i], bfr[j], acc[i][j], 0,0,0);
  }
  #pragma unroll
  for (int j=0;j<4;j++){
    int col = n0 + wn + j*16 + lr;
    float bb = bias[col];
    #pragma unroll
    for (int i=0;i<2;i++){
      int rowb = wm + i*16 + quad*4;
      #pragma unroll
      for (int r=0;r<4;r++)
        out[(size_t)(rowb+r)*768 + col] = f2bf(acc[i][j][r] + bb);
    }
  }
}

// ---------------- swapped-operand split-key MFMA flash attention ----------------
// S^T = mfma(K,Q): each lane owns ONE q-row (q = lane&15) -> row-max = 2 shuffles,
// 1 alpha-exp2; P^T B-frag built with a single wave-local LDS b64x2-write/b128-read.
// PV swapped too: o^T = mfma(V^T, P^T) keeps (m,l) lane-local and gives float4 stores.
// grid (80,12), XCD-swizzled. bx 0..63: word, 32 q rows (2 groups x 16, key-split 2 ways).
// bx 64..79: entity, 16 q rows, keys split 2 ways across blocks + 4 ways across waves.
__global__ __launch_bounds__(256) void attn_split(
  const unsigned short* __restrict__ Kb,  const unsigned short* __restrict__ VbT,
  const unsigned short* __restrict__ Qw,  const unsigned short* __restrict__ Qwe,
  const unsigned short* __restrict__ Qew, const unsigned short* __restrict__ Qee,
  const float* __restrict__ am,
  float* __restrict__ outw, float* __restrict__ pO, float* __restrict__ pML)
{
  // XCD-aware swizzle: 960 blocks, 8 XCDs -> per-XCD contiguous head-major chunk.
  int lin = blockIdx.x + 80*blockIdx.y;
  int wid = (lin & 7)*120 + (lin >> 3);
  int bx = wid % 80;
  int h  = wid / 80;

  int tid = threadIdx.x, w = tid>>6, lane = tid&63, quad = lane>>4, lr = lane&15;
  bool isword = bx < 64;
  int qrb, kh, nsplit, eg=0, ehalf=0;
  const unsigned short *Qa, *Qb;
  if (isword){ qrb = bx*32 + (w>>1)*16; kh = w&1; nsplit = 2; Qa=Qw;  Qb=Qwe; }
  else       { int e = bx-64; eg = e>>1; ehalf = e&1;
               qrb = eg*16;             kh = w;   nsplit = 4; Qa=Qew; Qb=Qee; }
  int hofs = h*64;

  // union: per-wave P^T staging (16 rows x 20 u32, stride 80B = 16B-aligned) overlays
  // the epilogue merge buffer [4][64][20] f32. 20480 B total.
  __shared__ __align__(16) unsigned int shb[4*64*20];
  unsigned int* p32w = shb + w*320;

  const unsigned short* qr = Qa + (size_t)(qrb+lr)*768 + hofs + quad*8;
  bf16x8 qa0 = ldb(qr), qa1 = ldb(qr + 32);
  qr = Qb + (size_t)(qrb+lr)*768 + hofs + quad*8;
  bf16x8 qb0 = ldb(qr), qb1 = ldb(qr + 32);

  u16x8 onesu;
  #pragma unroll
  for (int i=0;i<8;i++) onesu[i] = 0x3F80;          // bf16 1.0
  bf16x8 onesf = __builtin_bit_cast(bf16x8, onesu);

  float m = -1e30f;
  f32x4 o[4], l4;
  #pragma unroll
  for (int r=0;r<4;r++) l4[r] = 0.f;
  #pragma unroll
  for (int n2=0;n2<4;n2++) for (int r=0;r<4;r++) o[n2][r] = 0.f;

  int lo, nw, start, end, step;
  if (isword){
    lo = qrb - 256; if (lo < 0) lo = 0; lo &= ~31;        // padded keys band-masked
    int hi = qrb + 272; if (hi > 2048) hi = 2048; hi = (hi + 31) & ~31;
    nw = (hi - lo) >> 5;
    start = kh; end = nw + 4; step = 2;
  } else {
    lo = 0; nw = 64;
    start = ehalf*34 + kh; end = ehalf*34 + 34; step = 4;  // 68 chunks, block-split 2 ways
  }
  int iq = qrb + lr;                                       // this lane's global q row

  for (int c = start; c < end; c += step){
    bool entp = c >= nw;
    int j0 = entp ? (2048 + (c-nw)*32) : (lo + c*32);

    // K A-frags (rows = keys) straight from global
    const unsigned short* kp = Kb + (size_t)(j0+lr)*768 + hofs + quad*8;
    bf16x8 k00 = ldb(kp),          k01 = ldb(kp + 32);
    bf16x8 k10 = ldb(kp + 16*768), k11 = ldb(kp + 16*768 + 32);
    // V^T A-frags (rows = dims) straight from global
    const unsigned short* vp = VbT + (size_t)(hofs + lr)*2176 + j0 + quad*8;
    bf16x8 va0 = ldb(vp), va1 = ldb(vp + 16*2176), va2 = ldb(vp + 32*2176), va3 = ldb(vp + 48*2176);
    // attention-mask values for this lane's 8 keys
    float4 am0 = *(const float4*)(am + j0 + quad*4);
    float4 am1 = *(const float4*)(am + j0 + 16 + quad*4);

    bf16x8 qf0 = entp ? qb0 : qa0;
    bf16x8 qf1 = entp ? qb1 : qa1;
    f32x4 st0 = {0.f,0.f,0.f,0.f}, st1 = {0.f,0.f,0.f,0.f};
    __builtin_amdgcn_s_setprio(1);
    st0 = __builtin_amdgcn_mfma_f32_16x16x32_bf16(k00, qf0, st0, 0,0,0);
    st0 = __builtin_amdgcn_mfma_f32_16x16x32_bf16(k01, qf1, st0, 0,0,0);
    st1 = __builtin_amdgcn_mfma_f32_16x16x32_bf16(k10, qf0, st1, 0,0,0);
    st1 = __builtin_amdgcn_mfma_f32_16x16x32_bf16(k11, qf1, st1, 0,0,0);
    __builtin_amdgcn_s_setprio(0);

    // scores: lane q=lr fixed, keys = j0 + t*16 + quad*4 + r
    float sc0[4], sc1[4];
    bool wband = isword && !entp;
    #pragma unroll
    for (int r=0;r<4;r++){
      {
        float amj = am0[r];
        float sv  = st0[r];
        if (wband){
          sv += (amj != 0.f) ? NEGV : 0.f;
          int j = j0 + quad*4 + r;
          bool ok = ((unsigned)(iq - j + 256) <= 512u) && (sv != 0.f);
          sv = ok ? sv : NEGV;
        }
        sc0[r] = sv * (LOG2E*0.125f) + amj * LOG2E;
      }
      {
        float amj = am1[r];
        float sv  = st1[r];
        if (wband){
          sv += (amj != 0.f) ? NEGV : 0.f;
          int j = j0 + 16 + quad*4 + r;
          bool ok = ((unsigned)(iq - j + 256) <= 512u) && (sv != 0.f);
          sv = ok ? sv : NEGV;
        }
        sc1[r] = sv * (LOG2E*0.125f) + amj * LOG2E;
      }
    }

    // row max: 7 in-reg + 2 cross-quad shuffles
    float mx = fmaxf(fmaxf(fmaxf(sc0[0],sc0[1]), fmaxf(sc0[2],sc0[3])),
                     fmaxf(fmaxf(sc1[0],sc1[1]), fmaxf(sc1[2],sc1[3])));
    mx = fmaxf(mx, __shfl_xor(mx, 16));
    mx = fmaxf(mx, __shfl_xor(mx, 32));
    float mn = fmaxf(m, mx);
    float alpha = exp2f(m - mn);
    m = mn;

    float p00 = exp2f(sc0[0]-mn), p01 = exp2f(sc0[1]-mn);
    float p02 = exp2f(sc0[2]-mn), p03 = exp2f(sc0[3]-mn);
    float p10 = exp2f(sc1[0]-mn), p11 = exp2f(sc1[1]-mn);
    float p12 = exp2f(sc1[2]-mn), p13 = exp2f(sc1[3]-mn);
    unsigned int x0 = (unsigned int)f2bf(p00) | ((unsigned int)f2bf(p01)<<16);
    unsigned int x1 = (unsigned int)f2bf(p02) | ((unsigned int)f2bf(p03)<<16);
    unsigned int x2 = (unsigned int)f2bf(p10) | ((unsigned int)f2bf(p11)<<16);
    unsigned int x3 = (unsigned int)f2bf(p12) | ((unsigned int)f2bf(p13)<<16);

    #pragma unroll
    for (int r=0;r<4;r++) l4[r] *= alpha;
    #pragma unroll
    for (int n2=0;n2<4;n2++)
      #pragma unroll
      for (int r=0;r<4;r++) o[n2][r] *= alpha;

    // wave-local transpose: row q=lr holds 32 keys as 16 u32; read back as B-frag b128
    unsigned int* row = p32w + lr*20;
    u32x2 w0v = {x0, x1};
    u32x2 w1v = {x2, x3};
    *(u32x2_a*)(row + quad*2)     = w0v;   // keys quad*8(.. via slot quad*2)  t0
    *(u32x2_a*)(row + 8 + quad*2) = w1v;   // t1
    bf16x8 pf = ldb((const unsigned short*)(p32w + lr*20 + quad*4));

    __builtin_amdgcn_s_setprio(1);
    o[0] = __builtin_amdgcn_mfma_f32_16x16x32_bf16(va0, pf, o[0], 0,0,0);
    o[1] = __builtin_amdgcn_mfma_f32_16x16x32_bf16(va1, pf, o[1], 0,0,0);
    o[2] = __builtin_amdgcn_mfma_f32_16x16x32_bf16(va2, pf, o[2], 0,0,0);
    o[3] = __builtin_amdgcn_mfma_f32_16x16x32_bf16(va3, pf, o[3], 0,0,0);
    l4   = __builtin_amdgcn_mfma_f32_16x16x32_bf16(onesf, pf, l4, 0,0,0);   // row sums
    __builtin_amdgcn_s_setprio(0);
  }

  // ---- cross-wave merge ----
  float lsc = l4[0];
  __syncthreads();                       // all waves done with p32 region
  {
    float* my = (float*)shb + ((size_t)(w*64 + lane))*20;
    my[0] = m; my[1] = lsc;
    #pragma unroll
    for (int n2=0;n2<4;n2++)
      #pragma unroll
      for (int r=0;r<4;r++) my[2+n2*4+r] = o[n2][r];
  }
  __syncthreads();
  if (kh == 0){
    for (int p=1; p<nsplit; p++){
      const float* pr = (float*)shb + ((size_t)((w+p)*64 + lane))*20;
      float m2 = pr[0], l2 = pr[1];
      float M  = fmaxf(m, m2);
      float e1 = exp2f(m-M), e2 = exp2f(m2-M);
      m = M;
      lsc = lsc*e1 + l2*e2;
      #pragma unroll
      for (int n2=0;n2<4;n2++)
        #pragma unroll
        for (int r=0;r<4;r++)
          o[n2][r] = o[n2][r]*e1 + pr[2+n2*4+r]*e2;
    }
    if (isword){
      float rinv = 1.f / lsc;
      #pragma unroll
      for (int n2=0;n2<4;n2++){
        float4 sv;
        sv.x = o[n2][0]*rinv; sv.y = o[n2][1]*rinv;
        sv.z = o[n2][2]*rinv; sv.w = o[n2][3]*rinv;
        *(float4*)(outw + (size_t)(qrb+lr)*768 + hofs + n2*16 + quad*4) = sv;
      }
    } else {
      int idx = (eg*12 + h)*2 + ehalf;
      float* po = pO + (size_t)idx*1024;
      #pragma unroll
      for (int n2=0;n2<4;n2++){
        float4 sv;
        sv.x = o[n2][0]; sv.y = o[n2][1]; sv.z = o[n2][2]; sv.w = o[n2][3];
        *(float4*)(po + lr*64 + n2*16 + quad*4) = sv;
      }
      if (quad == 0){
        float* pml = pML + (size_t)idx*32;
        pml[lr*2]     = m;
        pml[lr*2 + 1] = lsc;
      }
    }
  }
}

// ---------------- entity cross-block merge: 2 key-halves -> final output ----------------
__global__ __launch_bounds__(256) void merge_ent(
    const float* __restrict__ pO, const float* __restrict__ pML,
    float* __restrict__ oute)
{
  int b = blockIdx.x;            // 0..95 = eg*12 + h
  int g = b/12, h = b%12;
  int tid = threadIdx.x;
  int row = tid>>4, cg = tid&15;
  int i0 = b*2, i1 = b*2+1;
  float m0 = pML[(size_t)i0*32 + row*2], l0 = pML[(size_t)i0*32 + row*2 + 1];
  float m1 = pML[(size_t)i1*32 + row*2], l1 = pML[(size_t)i1*32 + row*2 + 1];
  float M  = fmaxf(m0, m1);
  float e0 = exp2f(m0-M), e1 = exp2f(m1-M);
  float rl = 1.f/(l0*e0 + l1*e1);
  float4 a = *(const float4*)(pO + (size_t)i0*1024 + row*64 + cg*4);
  float4 c = *(const float4*)(pO + (size_t)i1*1024 + row*64 + cg*4);
  float4 o;
  o.x = (a.x*e0 + c.x*e1)*rl;
  o.y = (a.y*e0 + c.y*e1)*rl;
  o.z = (a.z*e0 + c.z*e1)*rl;
  o.w = (a.w*e0 + c.w*e1)*rl;
  *(float4*)(oute + (size_t)(g*16+row)*768 + h*64 + cg*4) = o;
}

extern "C" void kernel_launch(void* const* d_in, const int* in_sizes, int n_in,
                              void* d_out, int out_size, void* d_ws, size_t ws_size,
                              hipStream_t stream) {
  const float* word  = (const float*)d_in[0];
  const float* ent   = (const float*)d_in[1];
  const float* am    = (const float*)d_in[2];
  const float* q_w   = (const float*)d_in[3];
  const float* q_b   = (const float*)d_in[4];
  const float* k_w   = (const float*)d_in[5];
  const float* k_b   = (const float*)d_in[6];
  const float* v_w   = (const float*)d_in[7];
  const float* v_b   = (const float*)d_in[8];
  const float* w2e_w = (const float*)d_in[9];
  const float* w2e_b = (const float*)d_in[10];
  const float* e2w_w = (const float*)d_in[11];
  const float* e2w_b = (const float*)d_in[12];
  const float* e2e_w = (const float*)d_in[13];
  const float* e2e_b = (const float*)d_in[14];

  unsigned short* ws  = (unsigned short*)d_ws;
  unsigned short* wT  = ws;                       // 6*768*768 bf16 (dead after gemm_proj)
  unsigned short* Kb  = wT  + (size_t)6*589824;   // 2176*768
  unsigned short* Vb  = Kb  + (size_t)2176*768;
  unsigned short* Qw  = Vb  + (size_t)2176*768;   // 2048*768
  unsigned short* Qwe = Qw  + (size_t)2048*768;
  unsigned short* Qew = Qwe + (size_t)2048*768;   // 128*768
  unsigned short* Qee = Qew + (size_t)128*768;
  unsigned short* VbT = Qee + (size_t)128*768;    // 768*2176
  unsigned short* Abf = VbT + (size_t)768*2176;   // 2176*768 bf16 concat activations

  // entity partials live in the dead wT region during attention
  float* pO  = (float*)wT;                        // 192 * 16*64 f32
  float* pML = pO + (size_t)192*1024;             // 192 * 16*2  f32

  float* outw = (float*)d_out;                    // fp32 output
  float* oute = outw + (size_t)2048*768;

  hipLaunchKernelGGL(cast_a, dim3(816), dim3(256), 0, stream, word, ent, Abf);
  hipLaunchKernelGGL(transpose6, dim3(24,24,6), dim3(32,8), 0, stream,
                     k_w, v_w, q_w, w2e_w, e2w_w, e2e_w, wT);
  hipLaunchKernelGGL(gemm_proj, dim3(136,6), dim3(256), 0, stream,
                     Abf, wT, k_b, v_b, q_b, w2e_b, e2w_b, e2e_b,
                     Kb, Vb, Qw, Qwe, Qew, Qee);
  hipLaunchKernelGGL(transpose_v, dim3(68,24), dim3(32,8), 0, stream, Vb, VbT);
  hipLaunchKernelGGL(attn_split, dim3(80,12), dim3(256), 0, stream,
                     Kb, VbT, Qw, Qwe, Qew, Qee, am, outw, pO, pML);
  hipLaunchKernelGGL(merge_ent, dim3(96), dim3(256), 0, stream,
                     pO, pML, oute);
}

// Round 4
// 172.768 us; speedup vs baseline: 1.1994x; 1.0453x over previous
//
#include <hip/hip_runtime.h>

typedef __bf16 bf16x8 __attribute__((ext_vector_type(8)));
typedef unsigned short u16x8 __attribute__((ext_vector_type(8)));
typedef u16x8 u16x8_a __attribute__((may_alias));
typedef unsigned int u32x2 __attribute__((ext_vector_type(2)));
typedef u32x2 u32x2_a __attribute__((may_alias));
typedef unsigned int u32x4 __attribute__((ext_vector_type(4)));
typedef u32x4 u32x4_a __attribute__((may_alias));
typedef float f32x4 __attribute__((ext_vector_type(4)));

#define LOG2E 1.4426950408889634f
#define NEGV  -10000.0f

__device__ __forceinline__ unsigned short f2bf(float f){
  union{float f; unsigned int i;} x; x.f=f;
  unsigned int i = x.i;
  return (unsigned short)((i + 0x7FFFu + ((i>>16)&1u)) >> 16);
}
__device__ __forceinline__ u16x8 cvt8(float4 a, float4 b){
  u16x8 r;
  r[0]=f2bf(a.x); r[1]=f2bf(a.y); r[2]=f2bf(a.z); r[3]=f2bf(a.w);
  r[4]=f2bf(b.x); r[5]=f2bf(b.y); r[6]=f2bf(b.z); r[7]=f2bf(b.w);
  return r;
}
__device__ __forceinline__ bf16x8 ldb(const unsigned short* p){
  return __builtin_bit_cast(bf16x8, *(const u16x8_a*)p);
}
// async global->LDS, 16B per lane, dest = wave-uniform base + lane*16
__device__ __forceinline__ void gload16(const unsigned short* g, unsigned short* l){
  __builtin_amdgcn_global_load_lds(
    (const __attribute__((address_space(1))) void*)g,
    (__attribute__((address_space(3))) void*)l, 16, 0, 0);
}

// ---------------- A cast: Abf[concat row][k] = bf16(concat(word,ent)), 2176x768 ----------------
__global__ __launch_bounds__(256) void cast_a(
    const float* __restrict__ word, const float* __restrict__ ent,
    unsigned short* __restrict__ Abf)
{
  size_t e = ((size_t)blockIdx.x*256 + threadIdx.x)*8;   // 816 blocks exact
  const size_t WE = (size_t)2048*768;
  const float* s = (e < WE) ? (word + e) : (ent + (e - WE));
  float4 a = *(const float4*)s;
  float4 b = *(const float4*)(s+4);
  *(u16x8_a*)(Abf + e) = cvt8(a,b);
}

// ---------------- weight transpose+cast: wT[g][n][k] = bf16(w[g][k][n]), 768x768 ----------------
__global__ __launch_bounds__(256) void transpose6(
    const float* __restrict__ w0, const float* __restrict__ w1,
    const float* __restrict__ w2, const float* __restrict__ w3,
    const float* __restrict__ w4, const float* __restrict__ w5,
    unsigned short* __restrict__ outT)
{
  const float* src;
  switch (blockIdx.z){
    case 0: src = w0; break; case 1: src = w1; break; case 2: src = w2; break;
    case 3: src = w3; break; case 4: src = w4; break; default: src = w5; break;
  }
  unsigned short* dst = outT + (size_t)blockIdx.z * 589824;
  __shared__ float tile[32][33];
  int tx = threadIdx.x, ty = threadIdx.y;
  int x0 = blockIdx.x*32, y0 = blockIdx.y*32;
  #pragma unroll
  for (int i=0;i<32;i+=8) tile[ty+i][tx] = src[(size_t)(y0+ty+i)*768 + x0+tx];
  __syncthreads();
  #pragma unroll
  for (int i=0;i<32;i+=8) dst[(size_t)(x0+ty+i)*768 + y0+tx] = f2bf(tile[tx][ty+i]);
}

// ---------------- V transpose: VbT[d][key] = Vb[key][d] (bf16, 2176x768 -> 768x2176) ----
__global__ __launch_bounds__(256) void transpose_v(
    const unsigned short* __restrict__ Vb, unsigned short* __restrict__ VbT)
{
  __shared__ unsigned short t[32][33];
  int tx = threadIdx.x, ty = threadIdx.y;
  int x0 = blockIdx.x*32;   // key
  int y0 = blockIdx.y*32;   // dim
  #pragma unroll
  for (int i=0;i<32;i+=8) t[ty+i][tx] = Vb[(size_t)(x0+ty+i)*768 + y0+tx];
  __syncthreads();
  #pragma unroll
  for (int i=0;i<32;i+=8) VbT[(size_t)(y0+ty+i)*2176 + x0+tx] = t[tx][ty+i];
}

// ---------------- batched projection GEMM: out = Abf(bf16) @ wT(bf16) + bias(fp32) ----------------
// 64x128 tiles, grid (136,6); staging via global_load_lds (16B DMA, no VGPR round-trip).
__global__ __launch_bounds__(256) void gemm_proj(
    const unsigned short* __restrict__ Abf,
    const unsigned short* __restrict__ wT,
    const float* __restrict__ bK, const float* __restrict__ bV,
    const float* __restrict__ bQ, const float* __restrict__ bWE,
    const float* __restrict__ bEW, const float* __restrict__ bEE,
    unsigned short* __restrict__ oK, unsigned short* __restrict__ oV,
    unsigned short* __restrict__ oQ, unsigned short* __restrict__ oWE,
    unsigned short* __restrict__ oEW, unsigned short* __restrict__ oEE)
{
  int mt = blockIdx.x, ntile = blockIdx.y;
  int g, mg;
  if      (mt <  34){ g=0; mg=mt;     }
  else if (mt <  68){ g=1; mg=mt-34;  }
  else if (mt < 100){ g=2; mg=mt-68;  }
  else if (mt < 132){ g=3; mg=mt-100; }
  else if (mt < 134){ g=4; mg=mt-132; }
  else              { g=5; mg=mt-134; }
  int m0 = mg*64;
  const unsigned short* A = Abf + (size_t)((g>=4 ? 2048 : 0) + m0)*768;
  const unsigned short* B = wT + (size_t)g*589824;
  const float* bias; unsigned short* out;
  switch (g){
    case 0: bias=bK;  out=oK;  break;
    case 1: bias=bV;  out=oV;  break;
    case 2: bias=bQ;  out=oQ;  break;
    case 3: bias=bWE; out=oWE; break;
    case 4: bias=bEW; out=oEW; break;
    default:bias=bEE; out=oEE; break;
  }
  out += (size_t)m0*768;
  int n0 = ntile*128;

  __shared__ __align__(16) unsigned short a_s[64*32];
  __shared__ __align__(16) unsigned short b_s[128*32];

  int tid  = threadIdx.x;
  int w    = tid>>6, lane = tid&63, quad = lane>>4, lr = lane&15;
  int wm   = (w&1)*32, wn = (w>>1)*64;

  f32x4 acc[2][4];
  #pragma unroll
  for (int i=0;i<2;i++) for (int j=0;j<4;j++) for (int r=0;r<4;r++) acc[i][j][r]=0.f;

  // DMA staging: wave w stages a_s rows w*16..+15 (1 instr) and b_s rows w*32..+31 (2 instrs)
  int srow = lane>>2;          // 0..15
  int scol = (lane&3)*8;       // element within 32-k row
  const unsigned short* gA  = A + (size_t)(w*16 + srow)*768 + scol;
  const unsigned short* gB0 = B + (size_t)(n0 + w*32 + srow)*768 + scol;
  const unsigned short* gB1 = gB0 + (size_t)16*768;
  unsigned short* lA  = a_s + w*16*32;
  unsigned short* lB0 = b_s + w*32*32;
  unsigned short* lB1 = b_s + w*32*32 + 16*32;

  for (int k0=0; k0<768; k0+=32){
    __syncthreads();                 // previous iter's frag reads complete
    gload16(gA  + k0, lA);
    gload16(gB0 + k0, lB0);
    gload16(gB1 + k0, lB1);
    __syncthreads();                 // vmcnt drained before barrier -> LDS ready
    bf16x8 af[2], bfr[4];
    #pragma unroll
    for (int i=0;i<2;i++) af[i]  = ldb(a_s + (wm+i*16+lr)*32 + quad*8);
    #pragma unroll
    for (int j=0;j<4;j++) bfr[j] = ldb(b_s + (wn+j*16+lr)*32 + quad*8);
    #pragma unroll
    for (int i=0;i<2;i++)
      #pragma unroll
      for (int j=0;j<4;j++)
        acc[i][j] = __builtin_amdgcn_mfma_f32_16x16x32_bf16(af[i], bfr[j], acc[i][j], 0,0,0);
  }
  #pragma unroll
  for (int j=0;j<4;j++){
    int col = n0 + wn + j*16 + lr;
    float bb = bias[col];
    #pragma unroll
    for (int i=0;i<2;i++){
      int rowb = wm + i*16 + quad*4;
      #pragma unroll
      for (int r=0;r<4;r++)
        out[(size_t)(rowb+r)*768 + col] = f2bf(acc[i][j][r] + bb);
    }
  }
}

// ---------------- swapped-operand split-key MFMA flash attention, 64 keys/iteration ----------------
// S^T = mfma(K,Q): lane owns one q-row (lr); two 32-key chunks per iteration share one
// combined max (2 shuffles), one alpha, one LDS round-trip. Odd remainder -> phantom chunk
// (scores forced to -1e30 => p=0). grid (80,12), XCD-swizzled.
__global__ __launch_bounds__(256) void attn_split(
  const unsigned short* __restrict__ Kb,  const unsigned short* __restrict__ VbT,
  const unsigned short* __restrict__ Qw,  const unsigned short* __restrict__ Qwe,
  const unsigned short* __restrict__ Qew, const unsigned short* __restrict__ Qee,
  const float* __restrict__ am,
  float* __restrict__ outw, float* __restrict__ pO, float* __restrict__ pML)
{
  // XCD-aware swizzle: 960 blocks, 8 XCDs -> per-XCD contiguous head-major chunk.
  int lin = blockIdx.x + 80*blockIdx.y;
  int wid = (lin & 7)*120 + (lin >> 3);
  int bx = wid % 80;
  int h  = wid / 80;

  int tid = threadIdx.x, w = tid>>6, lane = tid&63, quad = lane>>4, lr = lane&15;
  bool isword = bx < 64;
  int qrb, kh, nsplit, eg=0, ehalf=0;
  const unsigned short *Qa, *Qb;
  if (isword){ qrb = bx*32 + (w>>1)*16; kh = w&1; nsplit = 2; Qa=Qw;  Qb=Qwe; }
  else       { int e = bx-64; eg = e>>1; ehalf = e&1;
               qrb = eg*16;             kh = w;   nsplit = 4; Qa=Qew; Qb=Qee; }
  int hofs = h*64;

  // union: per-wave P^T staging (16 rows x 44 u32, 2-way-bank-free) overlays the
  // epilogue merge buffer [4][64][21] f32 (stride 21 kills 8-way conflicts). 21504 B.
  __shared__ __align__(16) unsigned int shb[4*64*21];
  unsigned int* p32w = shb + w*(16*44);

  const unsigned short* qr = Qa + (size_t)(qrb+lr)*768 + hofs + quad*8;
  bf16x8 qa0 = ldb(qr), qa1 = ldb(qr + 32);
  qr = Qb + (size_t)(qrb+lr)*768 + hofs + quad*8;
  bf16x8 qb0 = ldb(qr), qb1 = ldb(qr + 32);

  u16x8 onesu;
  #pragma unroll
  for (int i=0;i<8;i++) onesu[i] = 0x3F80;          // bf16 1.0
  bf16x8 onesf = __builtin_bit_cast(bf16x8, onesu);

  float m = -1e30f;
  f32x4 o[4], l4;
  #pragma unroll
  for (int r=0;r<4;r++) l4[r] = 0.f;
  #pragma unroll
  for (int n2=0;n2<4;n2++) for (int r=0;r<4;r++) o[n2][r] = 0.f;

  int lo, nw, start, end, step;
  if (isword){
    lo = qrb - 256; if (lo < 0) lo = 0; lo &= ~31;        // padded keys band-masked
    int hi = qrb + 272; if (hi > 2048) hi = 2048; hi = (hi + 31) & ~31;
    nw = (hi - lo) >> 5;
    start = kh; end = nw + 4; step = 2;
  } else {
    lo = 0; nw = 64;
    start = ehalf*34 + kh; end = ehalf*34 + 34; step = 4;  // 68 chunks, block-split 2 ways
  }
  int iq = qrb + lr;                                       // this lane's global q row

  for (int c = start; c < end; c += 2*step){
    int c2r = c + step;
    bool ph = (c2r >= end);
    int c2 = ph ? c : c2r;

    bool entp1 = c  >= nw;  int j1 = entp1 ? (2048 + (c -nw)*32) : (lo + c *32);
    bool entp2 = c2 >= nw;  int j2 = entp2 ? (2048 + (c2-nw)*32) : (lo + c2*32);

    // K A-frags for both chunks
    const unsigned short* kp1 = Kb + (size_t)(j1+lr)*768 + hofs + quad*8;
    bf16x8 kA0 = ldb(kp1),          kA1 = ldb(kp1 + 32);
    bf16x8 kA2 = ldb(kp1 + 16*768), kA3 = ldb(kp1 + 16*768 + 32);
    const unsigned short* kp2 = Kb + (size_t)(j2+lr)*768 + hofs + quad*8;
    bf16x8 kB0 = ldb(kp2),          kB1 = ldb(kp2 + 32);
    bf16x8 kB2 = ldb(kp2 + 16*768), kB3 = ldb(kp2 + 16*768 + 32);
    // V^T A-frags chunk 1
    const unsigned short* vp1 = VbT + (size_t)(hofs + lr)*2176 + j1 + quad*8;
    bf16x8 v10 = ldb(vp1), v11 = ldb(vp1 + 16*2176), v12 = ldb(vp1 + 32*2176), v13 = ldb(vp1 + 48*2176);
    // attention-mask values
    float4 amA0 = *(const float4*)(am + j1 + quad*4);
    float4 amA1 = *(const float4*)(am + j1 + 16 + quad*4);
    float4 amB0 = *(const float4*)(am + j2 + quad*4);
    float4 amB1 = *(const float4*)(am + j2 + 16 + quad*4);

    bf16x8 qf10 = entp1 ? qb0 : qa0, qf11 = entp1 ? qb1 : qa1;
    bf16x8 qf20 = entp2 ? qb0 : qa0, qf21 = entp2 ? qb1 : qa1;

    f32x4 sA0 = {0.f,0.f,0.f,0.f}, sA1 = {0.f,0.f,0.f,0.f};
    f32x4 sB0 = {0.f,0.f,0.f,0.f}, sB1 = {0.f,0.f,0.f,0.f};
    __builtin_amdgcn_s_setprio(1);
    sA0 = __builtin_amdgcn_mfma_f32_16x16x32_bf16(kA0, qf10, sA0, 0,0,0);
    sA0 = __builtin_amdgcn_mfma_f32_16x16x32_bf16(kA1, qf11, sA0, 0,0,0);
    sA1 = __builtin_amdgcn_mfma_f32_16x16x32_bf16(kA2, qf10, sA1, 0,0,0);
    sA1 = __builtin_amdgcn_mfma_f32_16x16x32_bf16(kA3, qf11, sA1, 0,0,0);
    sB0 = __builtin_amdgcn_mfma_f32_16x16x32_bf16(kB0, qf20, sB0, 0,0,0);
    sB0 = __builtin_amdgcn_mfma_f32_16x16x32_bf16(kB1, qf21, sB0, 0,0,0);
    sB1 = __builtin_amdgcn_mfma_f32_16x16x32_bf16(kB2, qf20, sB1, 0,0,0);
    sB1 = __builtin_amdgcn_mfma_f32_16x16x32_bf16(kB3, qf21, sB1, 0,0,0);
    __builtin_amdgcn_s_setprio(0);

    float scA0[4], scA1[4], scB0[4], scB1[4];
    bool wb1 = isword && !entp1;
    bool wb2 = isword && !entp2;
    #pragma unroll
    for (int r=0;r<4;r++){
      { float amj = amA0[r], sv = sA0[r];
        if (wb1){ sv += (amj != 0.f) ? NEGV : 0.f;
          int j = j1 + quad*4 + r;
          bool ok = ((unsigned)(iq - j + 256) <= 512u) && (sv != 0.f);
          sv = ok ? sv : NEGV; }
        scA0[r] = sv * (LOG2E*0.125f) + amj * LOG2E; }
      { float amj = amA1[r], sv = sA1[r];
        if (wb1){ sv += (amj != 0.f) ? NEGV : 0.f;
          int j = j1 + 16 + quad*4 + r;
          bool ok = ((unsigned)(iq - j + 256) <= 512u) && (sv != 0.f);
          sv = ok ? sv : NEGV; }
        scA1[r] = sv * (LOG2E*0.125f) + amj * LOG2E; }
      { float amj = amB0[r], sv = sB0[r];
        if (wb2){ sv += (amj != 0.f) ? NEGV : 0.f;
          int j = j2 + quad*4 + r;
          bool ok = ((unsigned)(iq - j + 256) <= 512u) && (sv != 0.f);
          sv = ok ? sv : NEGV; }
        scB0[r] = sv * (LOG2E*0.125f) + amj * LOG2E; }
      { float amj = amB1[r], sv = sB1[r];
        if (wb2){ sv += (amj != 0.f) ? NEGV : 0.f;
          int j = j2 + 16 + quad*4 + r;
          bool ok = ((unsigned)(iq - j + 256) <= 512u) && (sv != 0.f);
          sv = ok ? sv : NEGV; }
        scB1[r] = sv * (LOG2E*0.125f) + amj * LOG2E; }
    }
    if (ph){
      #pragma unroll
      for (int r=0;r<4;r++){ scB0[r] = -1e30f; scB1[r] = -1e30f; }
    }

    // combined row max over 16 values: 2 cross-quad shuffles only
    float mx = fmaxf(
      fmaxf(fmaxf(fmaxf(scA0[0],scA0[1]), fmaxf(scA0[2],scA0[3])),
            fmaxf(fmaxf(scA1[0],scA1[1]), fmaxf(scA1[2],scA1[3]))),
      fmaxf(fmaxf(fmaxf(scB0[0],scB0[1]), fmaxf(scB0[2],scB0[3])),
            fmaxf(fmaxf(scB1[0],scB1[1]), fmaxf(scB1[2],scB1[3]))));
    mx = fmaxf(mx, __shfl_xor(mx, 16));
    mx = fmaxf(mx, __shfl_xor(mx, 32));
    float mn = fmaxf(m, mx);
    float alpha = exp2f(m - mn);
    m = mn;

    unsigned int xA0 = (unsigned int)f2bf(exp2f(scA0[0]-mn)) | ((unsigned int)f2bf(exp2f(scA0[1]-mn))<<16);
    unsigned int xA1 = (unsigned int)f2bf(exp2f(scA0[2]-mn)) | ((unsigned int)f2bf(exp2f(scA0[3]-mn))<<16);
    unsigned int xA2 = (unsigned int)f2bf(exp2f(scA1[0]-mn)) | ((unsigned int)f2bf(exp2f(scA1[1]-mn))<<16);
    unsigned int xA3 = (unsigned int)f2bf(exp2f(scA1[2]-mn)) | ((unsigned int)f2bf(exp2f(scA1[3]-mn))<<16);
    unsigned int xB0 = (unsigned int)f2bf(exp2f(scB0[0]-mn)) | ((unsigned int)f2bf(exp2f(scB0[1]-mn))<<16);
    unsigned int xB1 = (unsigned int)f2bf(exp2f(scB0[2]-mn)) | ((unsigned int)f2bf(exp2f(scB0[3]-mn))<<16);
    unsigned int xB2 = (unsigned int)f2bf(exp2f(scB1[0]-mn)) | ((unsigned int)f2bf(exp2f(scB1[1]-mn))<<16);
    unsigned int xB3 = (unsigned int)f2bf(exp2f(scB1[2]-mn)) | ((unsigned int)f2bf(exp2f(scB1[3]-mn))<<16);

    #pragma unroll
    for (int r=0;r<4;r++) l4[r] *= alpha;
    #pragma unroll
    for (int n2=0;n2<4;n2++)
      #pragma unroll
      for (int r=0;r<4;r++) o[n2][r] *= alpha;

    // wave-local transpose: row q=lr holds 64 keys as 32 u32 (words 0..15 chunk1, 16..31 chunk2)
    unsigned int* row = p32w + lr*44;
    u32x2 wv0 = {xA0, xA1};
    u32x2 wv1 = {xA2, xA3};
    u32x2 wv2 = {xB0, xB1};
    u32x2 wv3 = {xB2, xB3};
    *(u32x2_a*)(row + quad*2)      = wv0;
    *(u32x2_a*)(row + 8  + quad*2) = wv1;
    *(u32x2_a*)(row + 16 + quad*2) = wv2;
    *(u32x2_a*)(row + 24 + quad*2) = wv3;
    bf16x8 pf1 = ldb((const unsigned short*)(p32w + lr*44 + quad*4));
    bf16x8 pf2 = ldb((const unsigned short*)(p32w + lr*44 + 16 + quad*4));

    __builtin_amdgcn_s_setprio(1);
    o[0] = __builtin_amdgcn_mfma_f32_16x16x32_bf16(v10, pf1, o[0], 0,0,0);
    o[1] = __builtin_amdgcn_mfma_f32_16x16x32_bf16(v11, pf1, o[1], 0,0,0);
    o[2] = __builtin_amdgcn_mfma_f32_16x16x32_bf16(v12, pf1, o[2], 0,0,0);
    o[3] = __builtin_amdgcn_mfma_f32_16x16x32_bf16(v13, pf1, o[3], 0,0,0);
    l4   = __builtin_amdgcn_mfma_f32_16x16x32_bf16(onesf, pf1, l4, 0,0,0);
    __builtin_amdgcn_s_setprio(0);

    // V^T chunk 2 (regs reuse dead K frags; latency covered by PV1)
    const unsigned short* vp2 = VbT + (size_t)(hofs + lr)*2176 + j2 + quad*8;
    bf16x8 v20 = ldb(vp2), v21 = ldb(vp2 + 16*2176), v22 = ldb(vp2 + 32*2176), v23 = ldb(vp2 + 48*2176);

    __builtin_amdgcn_s_setprio(1);
    o[0] = __builtin_amdgcn_mfma_f32_16x16x32_bf16(v20, pf2, o[0], 0,0,0);
    o[1] = __builtin_amdgcn_mfma_f32_16x16x32_bf16(v21, pf2, o[1], 0,0,0);
    o[2] = __builtin_amdgcn_mfma_f32_16x16x32_bf16(v22, pf2, o[2], 0,0,0);
    o[3] = __builtin_amdgcn_mfma_f32_16x16x32_bf16(v23, pf2, o[3], 0,0,0);
    l4   = __builtin_amdgcn_mfma_f32_16x16x32_bf16(onesf, pf2, l4, 0,0,0);
    __builtin_amdgcn_s_setprio(0);
  }

  // ---- cross-wave merge ----
  float lsc = l4[0];
  __syncthreads();                       // all waves done with p32 region
  {
    float* my = (float*)shb + ((size_t)(w*64 + lane))*21;
    my[0] = m; my[1] = lsc;
    #pragma unroll
    for (int n2=0;n2<4;n2++)
      #pragma unroll
      for (int r=0;r<4;r++) my[2+n2*4+r] = o[n2][r];
  }
  __syncthreads();
  if (kh == 0){
    for (int p=1; p<nsplit; p++){
      const float* pr = (float*)shb + ((size_t)((w+p)*64 + lane))*21;
      float m2 = pr[0], l2 = pr[1];
      float M  = fmaxf(m, m2);
      float e1 = exp2f(m-M), e2 = exp2f(m2-M);
      m = M;
      lsc = lsc*e1 + l2*e2;
      #pragma unroll
      for (int n2=0;n2<4;n2++)
        #pragma unroll
        for (int r=0;r<4;r++)
          o[n2][r] = o[n2][r]*e1 + pr[2+n2*4+r]*e2;
    }
    if (isword){
      float rinv = 1.f / lsc;
      #pragma unroll
      for (int n2=0;n2<4;n2++){
        float4 sv;
        sv.x = o[n2][0]*rinv; sv.y = o[n2][1]*rinv;
        sv.z = o[n2][2]*rinv; sv.w = o[n2][3]*rinv;
        *(float4*)(outw + (size_t)(qrb+lr)*768 + hofs + n2*16 + quad*4) = sv;
      }
    } else {
      int idx = (eg*12 + h)*2 + ehalf;
      float* po = pO + (size_t)idx*1024;
      #pragma unroll
      for (int n2=0;n2<4;n2++){
        float4 sv;
        sv.x = o[n2][0]; sv.y = o[n2][1]; sv.z = o[n2][2]; sv.w = o[n2][3];
        *(float4*)(po + lr*64 + n2*16 + quad*4) = sv;
      }
      if (quad == 0){
        float* pml = pML + (size_t)idx*32;
        pml[lr*2]     = m;
        pml[lr*2 + 1] = lsc;
      }
    }
  }
}

// ---------------- entity cross-block merge: 2 key-halves -> final output ----------------
__global__ __launch_bounds__(256) void merge_ent(
    const float* __restrict__ pO, const float* __restrict__ pML,
    float* __restrict__ oute)
{
  int b = blockIdx.x;            // 0..95 = eg*12 + h
  int g = b/12, h = b%12;
  int tid = threadIdx.x;
  int row = tid>>4, cg = tid&15;
  int i0 = b*2, i1 = b*2+1;
  float m0 = pML[(size_t)i0*32 + row*2], l0 = pML[(size_t)i0*32 + row*2 + 1];
  float m1 = pML[(size_t)i1*32 + row*2], l1 = pML[(size_t)i1*32 + row*2 + 1];
  float M  = fmaxf(m0, m1);
  float e0 = exp2f(m0-M), e1 = exp2f(m1-M);
  float rl = 1.f/(l0*e0 + l1*e1);
  float4 a = *(const float4*)(pO + (size_t)i0*1024 + row*64 + cg*4);
  float4 c = *(const float4*)(pO + (size_t)i1*1024 + row*64 + cg*4);
  float4 o;
  o.x = (a.x*e0 + c.x*e1)*rl;
  o.y = (a.y*e0 + c.y*e1)*rl;
  o.z = (a.z*e0 + c.z*e1)*rl;
  o.w = (a.w*e0 + c.w*e1)*rl;
  *(float4*)(oute + (size_t)(g*16+row)*768 + h*64 + cg*4) = o;
}

extern "C" void kernel_launch(void* const* d_in, const int* in_sizes, int n_in,
                              void* d_out, int out_size, void* d_ws, size_t ws_size,
                              hipStream_t stream) {
  const float* word  = (const float*)d_in[0];
  const float* ent   = (const float*)d_in[1];
  const float* am    = (const float*)d_in[2];
  const float* q_w   = (const float*)d_in[3];
  const float* q_b   = (const float*)d_in[4];
  const float* k_w   = (const float*)d_in[5];
  const float* k_b   = (const float*)d_in[6];
  const float* v_w   = (const float*)d_in[7];
  const float* v_b   = (const float*)d_in[8];
  const float* w2e_w = (const float*)d_in[9];
  const float* w2e_b = (const float*)d_in[10];
  const float* e2w_w = (const float*)d_in[11];
  const float* e2w_b = (const float*)d_in[12];
  const float* e2e_w = (const float*)d_in[13];
  const float* e2e_b = (const float*)d_in[14];

  unsigned short* ws  = (unsigned short*)d_ws;
  unsigned short* wT  = ws;                       // 6*768*768 bf16 (dead after gemm_proj)
  unsigned short* Kb  = wT  + (size_t)6*589824;   // 2176*768
  unsigned short* Vb  = Kb  + (size_t)2176*768;
  unsigned short* Qw  = Vb  + (size_t)2176*768;   // 2048*768
  unsigned short* Qwe = Qw  + (size_t)2048*768;
  unsigned short* Qew = Qwe + (size_t)2048*768;   // 128*768
  unsigned short* Qee = Qew + (size_t)128*768;
  unsigned short* VbT = Qee + (size_t)128*768;    // 768*2176
  unsigned short* Abf = VbT + (size_t)768*2176;   // 2176*768 bf16 concat activations

  // entity partials live in the dead wT region during attention
  float* pO  = (float*)wT;                        // 192 * 16*64 f32
  float* pML = pO + (size_t)192*1024;             // 192 * 16*2  f32

  float* outw = (float*)d_out;                    // fp32 output
  float* oute = outw + (size_t)2048*768;

  hipLaunchKernelGGL(cast_a, dim3(816), dim3(256), 0, stream, word, ent, Abf);
  hipLaunchKernelGGL(transpose6, dim3(24,24,6), dim3(32,8), 0, stream,
                     k_w, v_w, q_w, w2e_w, e2w_w, e2e_w, wT);
  hipLaunchKernelGGL(gemm_proj, dim3(136,6), dim3(256), 0, stream,
                     Abf, wT, k_b, v_b, q_b, w2e_b, e2w_b, e2e_b,
                     Kb, Vb, Qw, Qwe, Qew, Qee);
  hipLaunchKernelGGL(transpose_v, dim3(68,24), dim3(32,8), 0, stream, Vb, VbT);
  hipLaunchKernelGGL(attn_split, dim3(80,12), dim3(256), 0, stream,
                     Kb, VbT, Qw, Qwe, Qew, Qee, am, outw, pO, pML);
  hipLaunchKernelGGL(merge_ent, dim3(96), dim3(256), 0, stream,
                     pO, pML, oute);
}

// Round 6
// 169.426 us; speedup vs baseline: 1.2231x; 1.0197x over previous
//
#include <hip/hip_runtime.h>

typedef __bf16 bf16x8 __attribute__((ext_vector_type(8)));
typedef unsigned short u16x8 __attribute__((ext_vector_type(8)));
typedef u16x8 u16x8_a __attribute__((may_alias));
typedef unsigned int u32x2 __attribute__((ext_vector_type(2)));
typedef u32x2 u32x2_a __attribute__((may_alias));
typedef unsigned int u32x4 __attribute__((ext_vector_type(4)));
typedef u32x4 u32x4_a __attribute__((may_alias));
typedef float f32x4 __attribute__((ext_vector_type(4)));

#define LOG2E 1.4426950408889634f
#define NEGV  -10000.0f

// packed f32->bf16 (RNE), 2 at a time, single HW instruction
__device__ __forceinline__ unsigned int cvtpk(float lo, float hi){
  unsigned int r;
  asm("v_cvt_pk_bf16_f32 %0, %1, %2" : "=v"(r) : "v"(lo), "v"(hi));
  return r;
}
__device__ __forceinline__ bf16x8 ldb(const unsigned short* p){
  return __builtin_bit_cast(bf16x8, *(const u16x8_a*)p);
}
// async global->LDS, 16B per lane, dest = wave-uniform base + lane*16
__device__ __forceinline__ void gload16(const unsigned short* g, unsigned short* l){
  __builtin_amdgcn_global_load_lds(
    (const __attribute__((address_space(1))) void*)g,
    (__attribute__((address_space(3))) void*)l, 16, 0, 0);
}

// ---------------- fused prep: weight transpose+cast | A cast | mask tables ----------------
// z<6 : wT[g][n][k] = bf16(w[g][k][n])       (x<24, y<24)
// z==6: Abf = bf16(concat(word,ent))          (816 blocks = 24x34)
// z==7: amT[j]=am[j]*LOG2E, negT[j]=(am!=0?NEGV:0)   (y==0, x<9)
__global__ __launch_bounds__(256) void prep(
    const float* __restrict__ w0, const float* __restrict__ w1,
    const float* __restrict__ w2, const float* __restrict__ w3,
    const float* __restrict__ w4, const float* __restrict__ w5,
    const float* __restrict__ word, const float* __restrict__ ent,
    const float* __restrict__ am,
    unsigned short* __restrict__ outT, unsigned short* __restrict__ Abf,
    float* __restrict__ amT, float* __restrict__ negT)
{
  int z = blockIdx.z, tid = threadIdx.x;
  if (z == 6){
    size_t id = (size_t)blockIdx.y*24 + blockIdx.x;
    size_t e = (id*256 + tid)*8;
    const size_t WE = (size_t)2048*768;
    const float* s = (e < WE) ? (word + e) : (ent + (e - WE));
    float4 a = *(const float4*)s;
    float4 b = *(const float4*)(s+4);
    u32x4 v = {cvtpk(a.x,a.y), cvtpk(a.z,a.w), cvtpk(b.x,b.y), cvtpk(b.z,b.w)};
    *(u32x4_a*)(Abf + e) = v;
    return;
  }
  if (z == 7){
    if (blockIdx.y != 0 || blockIdx.x >= 9) return;
    int j = blockIdx.x*256 + tid;
    if (j < 2176){
      float a = am[j];
      amT[j]  = a * LOG2E;
      negT[j] = (a != 0.f) ? NEGV : 0.f;
    }
    return;
  }
  if (blockIdx.y >= 24) return;
  const float* src;
  switch (z){
    case 0: src = w0; break; case 1: src = w1; break; case 2: src = w2; break;
    case 3: src = w3; break; case 4: src = w4; break; default: src = w5; break;
  }
  unsigned short* dst = outT + (size_t)z * 589824;
  __shared__ float tile[32][33];
  int tx = tid & 31, ty = tid >> 5;
  int x0 = blockIdx.x*32, y0 = blockIdx.y*32;
  #pragma unroll
  for (int i=0;i<32;i+=8) tile[ty+i][tx] = src[(size_t)(y0+ty+i)*768 + x0+tx];
  __syncthreads();
  #pragma unroll
  for (int i=0;i<32;i+=16){
    unsigned int u = cvtpk(tile[tx][ty+i], tile[tx][ty+i+8]);
    dst[(size_t)(x0+ty+i)*768 + y0+tx]   = (unsigned short)u;
    dst[(size_t)(x0+ty+i+8)*768 + y0+tx] = (unsigned short)(u>>16);
  }
}

// ---------------- batched projection GEMM, 128x128 tiles (m97 structure) ----------------
// out = Abf(bf16) @ wT(bf16) + bias. grid (68,6) = 408 blocks.
// g==1 (V) writes VbT[d][key] directly (transposed epilogue) - no Vb, no transpose_v.
__global__ __launch_bounds__(256) void gemm_proj(
    const unsigned short* __restrict__ Abf,
    const unsigned short* __restrict__ wT,
    const float* __restrict__ bK, const float* __restrict__ bV,
    const float* __restrict__ bQ, const float* __restrict__ bWE,
    const float* __restrict__ bEW, const float* __restrict__ bEE,
    unsigned short* __restrict__ oK, unsigned short* __restrict__ VbT,
    unsigned short* __restrict__ oQ, unsigned short* __restrict__ oWE,
    unsigned short* __restrict__ oEW, unsigned short* __restrict__ oEE)
{
  int mt = blockIdx.x, ntile = blockIdx.y;
  int g, mg;
  if      (mt < 17){ g=0; mg=mt;    }
  else if (mt < 34){ g=1; mg=mt-17; }
  else if (mt < 50){ g=2; mg=mt-34; }
  else if (mt < 66){ g=3; mg=mt-50; }
  else if (mt < 67){ g=4; mg=0;     }
  else             { g=5; mg=0;     }
  int m0 = mg*128;
  const unsigned short* A = Abf + (size_t)((g>=4 ? 2048 : 0) + m0)*768;
  const unsigned short* B = wT + (size_t)g*589824;
  const float* bias; unsigned short* out;
  switch (g){
    case 0: bias=bK;  out=oK;  break;
    case 1: bias=bV;  out=0;   break;
    case 2: bias=bQ;  out=oQ;  break;
    case 3: bias=bWE; out=oWE; break;
    case 4: bias=bEW; out=oEW; break;
    default:bias=bEE; out=oEE; break;
  }
  int n0 = ntile*128;

  __shared__ __align__(16) unsigned short a_s[128*32];
  __shared__ __align__(16) unsigned short b_s[128*32];

  int tid  = threadIdx.x;
  int w    = tid>>6, lane = tid&63, quad = lane>>4, lr = lane&15;
  int wm   = (w&1)*64, wn = (w>>1)*64;

  f32x4 acc[4][4];
  #pragma unroll
  for (int i=0;i<4;i++) for (int j=0;j<4;j++) for (int r=0;r<4;r++) acc[i][j][r]=0.f;

  // DMA staging: wave w stages 32 A-rows and 32 B-rows (2 gload16 each)
  int srow = lane>>2;          // 0..15
  int scol = (lane&3)*8;
  const unsigned short* gA0 = A + (size_t)(w*32 + srow)*768 + scol;
  const unsigned short* gA1 = gA0 + (size_t)16*768;
  const unsigned short* gB0 = B + (size_t)(n0 + w*32 + srow)*768 + scol;
  const unsigned short* gB1 = gB0 + (size_t)16*768;
  unsigned short* lA0 = a_s + w*32*32;
  unsigned short* lA1 = lA0 + 16*32;
  unsigned short* lB0 = b_s + w*32*32;
  unsigned short* lB1 = lB0 + 16*32;

  for (int k0=0; k0<768; k0+=32){
    __syncthreads();                 // previous iter's frag reads complete
    gload16(gA0 + k0, lA0);
    gload16(gA1 + k0, lA1);
    gload16(gB0 + k0, lB0);
    gload16(gB1 + k0, lB1);
    __syncthreads();                 // vmcnt drained before barrier -> LDS ready
    bf16x8 af[4], bfr[4];
    #pragma unroll
    for (int i=0;i<4;i++) af[i]  = ldb(a_s + (wm+i*16+lr)*32 + quad*8);
    #pragma unroll
    for (int j=0;j<4;j++) bfr[j] = ldb(b_s + (wn+j*16+lr)*32 + quad*8);
    #pragma unroll
    for (int i=0;i<4;i++)
      #pragma unroll
      for (int j=0;j<4;j++)
        acc[i][j] = __builtin_amdgcn_mfma_f32_16x16x32_bf16(af[i], bfr[j], acc[i][j], 0,0,0);
  }
  if (g == 1){
    // transposed epilogue: VbT[col][m0+row], 4 consecutive keys -> one 8B store
    #pragma unroll
    for (int j=0;j<4;j++){
      int col = n0 + wn + j*16 + lr;
      float bb = bias[col];
      #pragma unroll
      for (int i=0;i<4;i++){
        int rowb = m0 + wm + i*16 + quad*4;
        u32x2 uv = {cvtpk(acc[i][j][0]+bb, acc[i][j][1]+bb),
                    cvtpk(acc[i][j][2]+bb, acc[i][j][3]+bb)};
        *(u32x2_a*)(VbT + (size_t)col*2176 + rowb) = uv;
      }
    }
  } else {
    out += (size_t)m0*768;
    #pragma unroll
    for (int j=0;j<4;j++){
      int col = n0 + wn + j*16 + lr;
      float bb = bias[col];
      #pragma unroll
      for (int i=0;i<4;i++){
        int rowb = wm + i*16 + quad*4;
        unsigned int u01 = cvtpk(acc[i][j][0]+bb, acc[i][j][1]+bb);
        unsigned int u23 = cvtpk(acc[i][j][2]+bb, acc[i][j][3]+bb);
        out[(size_t)(rowb+0)*768 + col] = (unsigned short)u01;
        out[(size_t)(rowb+1)*768 + col] = (unsigned short)(u01>>16);
        out[(size_t)(rowb+2)*768 + col] = (unsigned short)u23;
        out[(size_t)(rowb+3)*768 + col] = (unsigned short)(u23>>16);
      }
    }
  }
}

// ---------------- swapped-operand split-key MFMA flash attention, 64 keys/iteration ----------------
// S^T = mfma(K,Q): lane owns one q-row (lr); two 32-key chunks per iteration share one
// combined max (2 shuffles), one alpha, one LDS round-trip. Odd remainder -> phantom chunk.
// Mask algebra uses precomputed amT/negT tables; P packing via v_cvt_pk_bf16_f32;
// wave-uniform defer-rescale skips the o/l rescale when max didn't grow.
__global__ __launch_bounds__(256) void attn_split(
  const unsigned short* __restrict__ Kb,  const unsigned short* __restrict__ VbT,
  const unsigned short* __restrict__ Qw,  const unsigned short* __restrict__ Qwe,
  const unsigned short* __restrict__ Qew, const unsigned short* __restrict__ Qee,
  const float* __restrict__ amT, const float* __restrict__ negT,
  float* __restrict__ outw, float* __restrict__ pO, float* __restrict__ pML)
{
  // XCD-aware swizzle: 960 blocks, 8 XCDs -> per-XCD contiguous head-major chunk.
  int lin = blockIdx.x + 80*blockIdx.y;
  int wid = (lin & 7)*120 + (lin >> 3);
  int bx = wid % 80;
  int h  = wid / 80;

  int tid = threadIdx.x, w = tid>>6, lane = tid&63, quad = lane>>4, lr = lane&15;
  bool isword = bx < 64;
  int qrb, kh, nsplit, eg=0, ehalf=0;
  const unsigned short *Qa, *Qb;
  if (isword){ qrb = bx*32 + (w>>1)*16; kh = w&1; nsplit = 2; Qa=Qw;  Qb=Qwe; }
  else       { int e = bx-64; eg = e>>1; ehalf = e&1;
               qrb = eg*16;             kh = w;   nsplit = 4; Qa=Qew; Qb=Qee; }
  int hofs = h*64;

  // union: per-wave P^T staging (16 rows x 44 u32) overlays the epilogue merge
  // buffer [4][64][21] f32 (stride 21 kills 8-way conflicts). 21504 B.
  __shared__ __align__(16) unsigned int shb[4*64*21];
  unsigned int* p32w = shb + w*(16*44);

  const unsigned short* qr = Qa + (size_t)(qrb+lr)*768 + hofs + quad*8;
  bf16x8 qa0 = ldb(qr), qa1 = ldb(qr + 32);
  qr = Qb + (size_t)(qrb+lr)*768 + hofs + quad*8;
  bf16x8 qb0 = ldb(qr), qb1 = ldb(qr + 32);

  u16x8 onesu;
  #pragma unroll
  for (int i=0;i<8;i++) onesu[i] = 0x3F80;          // bf16 1.0
  bf16x8 onesf = __builtin_bit_cast(bf16x8, onesu);

  float m = -1e30f;
  f32x4 o[4], l4;
  #pragma unroll
  for (int r=0;r<4;r++) l4[r] = 0.f;
  #pragma unroll
  for (int n2=0;n2<4;n2++) for (int r=0;r<4;r++) o[n2][r] = 0.f;

  int lo, nw, start, end, step;
  if (isword){
    lo = qrb - 256; if (lo < 0) lo = 0; lo &= ~31;        // padded keys band-masked
    int hi = qrb + 272; if (hi > 2048) hi = 2048; hi = (hi + 31) & ~31;
    nw = (hi - lo) >> 5;
    start = kh; end = nw + 4; step = 2;
  } else {
    lo = 0; nw = 64;
    start = ehalf*34 + kh; end = ehalf*34 + 34; step = 4;  // 68 chunks, block-split 2 ways
  }
  int iq = qrb + lr;                                       // this lane's global q row

  for (int c = start; c < end; c += 2*step){
    int c2r = c + step;
    bool ph = (c2r >= end);
    int c2 = ph ? c : c2r;

    bool entp1 = c  >= nw;  int j1 = entp1 ? (2048 + (c -nw)*32) : (lo + c *32);
    bool entp2 = c2 >= nw;  int j2 = entp2 ? (2048 + (c2-nw)*32) : (lo + c2*32);

    // K A-frags for both chunks
    const unsigned short* kp1 = Kb + (size_t)(j1+lr)*768 + hofs + quad*8;
    bf16x8 kA0 = ldb(kp1),          kA1 = ldb(kp1 + 32);
    bf16x8 kA2 = ldb(kp1 + 16*768), kA3 = ldb(kp1 + 16*768 + 32);
    const unsigned short* kp2 = Kb + (size_t)(j2+lr)*768 + hofs + quad*8;
    bf16x8 kB0 = ldb(kp2),          kB1 = ldb(kp2 + 32);
    bf16x8 kB2 = ldb(kp2 + 16*768), kB3 = ldb(kp2 + 16*768 + 32);
    // V^T A-frags chunk 1
    const unsigned short* vp1 = VbT + (size_t)(hofs + lr)*2176 + j1 + quad*8;
    bf16x8 v10 = ldb(vp1), v11 = ldb(vp1 + 16*2176), v12 = ldb(vp1 + 32*2176), v13 = ldb(vp1 + 48*2176);
    // mask tables for this lane's 8 keys per chunk
    float4 aA0 = *(const float4*)(amT + j1 + quad*4);
    float4 aA1 = *(const float4*)(amT + j1 + 16 + quad*4);
    float4 aB0 = *(const float4*)(amT + j2 + quad*4);
    float4 aB1 = *(const float4*)(amT + j2 + 16 + quad*4);
    float4 nA0 = *(const float4*)(negT + j1 + quad*4);
    float4 nA1 = *(const float4*)(negT + j1 + 16 + quad*4);
    float4 nB0 = *(const float4*)(negT + j2 + quad*4);
    float4 nB1 = *(const float4*)(negT + j2 + 16 + quad*4);

    bf16x8 qf10 = entp1 ? qb0 : qa0, qf11 = entp1 ? qb1 : qa1;
    bf16x8 qf20 = entp2 ? qb0 : qa0, qf21 = entp2 ? qb1 : qa1;

    f32x4 sA0 = {0.f,0.f,0.f,0.f}, sA1 = {0.f,0.f,0.f,0.f};
    f32x4 sB0 = {0.f,0.f,0.f,0.f}, sB1 = {0.f,0.f,0.f,0.f};
    __builtin_amdgcn_s_setprio(1);
    sA0 = __builtin_amdgcn_mfma_f32_16x16x32_bf16(kA0, qf10, sA0, 0,0,0);
    sA0 = __builtin_amdgcn_mfma_f32_16x16x32_bf16(kA1, qf11, sA0, 0,0,0);
    sA1 = __builtin_amdgcn_mfma_f32_16x16x32_bf16(kA2, qf10, sA1, 0,0,0);
    sA1 = __builtin_amdgcn_mfma_f32_16x16x32_bf16(kA3, qf11, sA1, 0,0,0);
    sB0 = __builtin_amdgcn_mfma_f32_16x16x32_bf16(kB0, qf20, sB0, 0,0,0);
    sB0 = __builtin_amdgcn_mfma_f32_16x16x32_bf16(kB1, qf21, sB0, 0,0,0);
    sB1 = __builtin_amdgcn_mfma_f32_16x16x32_bf16(kB2, qf20, sB1, 0,0,0);
    sB1 = __builtin_amdgcn_mfma_f32_16x16x32_bf16(kB3, qf21, sB1, 0,0,0);
    __builtin_amdgcn_s_setprio(0);

    float scA0[4], scA1[4], scB0[4], scB1[4];
    bool wb1 = isword && !entp1;
    bool wb2 = isword && !entp2;
    #pragma unroll
    for (int r=0;r<4;r++){
      { float sv = sA0[r];
        if (wb1){ sv += nA0[r];
          int j = j1 + quad*4 + r;
          bool ok = ((unsigned)(iq - j + 256) <= 512u) && (sv != 0.f);
          sv = ok ? sv : NEGV; }
        scA0[r] = sv * (LOG2E*0.125f) + aA0[r]; }
      { float sv = sA1[r];
        if (wb1){ sv += nA1[r];
          int j = j1 + 16 + quad*4 + r;
          bool ok = ((unsigned)(iq - j + 256) <= 512u) && (sv != 0.f);
          sv = ok ? sv : NEGV; }
        scA1[r] = sv * (LOG2E*0.125f) + aA1[r]; }
      { float sv = sB0[r];
        if (wb2){ sv += nB0[r];
          int j = j2 + quad*4 + r;
          bool ok = ((unsigned)(iq - j + 256) <= 512u) && (sv != 0.f);
          sv = ok ? sv : NEGV; }
        scB0[r] = sv * (LOG2E*0.125f) + aB0[r]; }
      { float sv = sB1[r];
        if (wb2){ sv += nB1[r];
          int j = j2 + 16 + quad*4 + r;
          bool ok = ((unsigned)(iq - j + 256) <= 512u) && (sv != 0.f);
          sv = ok ? sv : NEGV; }
        scB1[r] = sv * (LOG2E*0.125f) + aB1[r]; }
    }
    if (ph){
      #pragma unroll
      for (int r=0;r<4;r++){ scB0[r] = -1e30f; scB1[r] = -1e30f; }
    }

    // combined row max over 16 values: 2 cross-quad shuffles only
    float mx = fmaxf(
      fmaxf(fmaxf(fmaxf(scA0[0],scA0[1]), fmaxf(scA0[2],scA0[3])),
            fmaxf(fmaxf(scA1[0],scA1[1]), fmaxf(scA1[2],scA1[3]))),
      fmaxf(fmaxf(fmaxf(scB0[0],scB0[1]), fmaxf(scB0[2],scB0[3])),
            fmaxf(fmaxf(scB1[0],scB1[1]), fmaxf(scB1[2],scB1[3]))));
    mx = fmaxf(mx, __shfl_xor(mx, 16));
    mx = fmaxf(mx, __shfl_xor(mx, 32));

    float mn;
    if (__all(mx <= m)){
      mn = m;                                    // defer: no rescale needed
    } else {
      mn = fmaxf(m, mx);
      float alpha = exp2f(m - mn);
      m = mn;
      #pragma unroll
      for (int r=0;r<4;r++) l4[r] *= alpha;
      #pragma unroll
      for (int n2=0;n2<4;n2++)
        #pragma unroll
        for (int r=0;r<4;r++) o[n2][r] *= alpha;
    }

    unsigned int xA0 = cvtpk(exp2f(scA0[0]-mn), exp2f(scA0[1]-mn));
    unsigned int xA1 = cvtpk(exp2f(scA0[2]-mn), exp2f(scA0[3]-mn));
    unsigned int xA2 = cvtpk(exp2f(scA1[0]-mn), exp2f(scA1[1]-mn));
    unsigned int xA3 = cvtpk(exp2f(scA1[2]-mn), exp2f(scA1[3]-mn));
    unsigned int xB0 = cvtpk(exp2f(scB0[0]-mn), exp2f(scB0[1]-mn));
    unsigned int xB1 = cvtpk(exp2f(scB0[2]-mn), exp2f(scB0[3]-mn));
    unsigned int xB2 = cvtpk(exp2f(scB1[0]-mn), exp2f(scB1[1]-mn));
    unsigned int xB3 = cvtpk(exp2f(scB1[2]-mn), exp2f(scB1[3]-mn));

    // wave-local transpose: row q=lr holds 64 keys as 32 u32
    unsigned int* row = p32w + lr*44;
    u32x2 wv0 = {xA0, xA1};
    u32x2 wv1 = {xA2, xA3};
    u32x2 wv2 = {xB0, xB1};
    u32x2 wv3 = {xB2, xB3};
    *(u32x2_a*)(row + quad*2)      = wv0;
    *(u32x2_a*)(row + 8  + quad*2) = wv1;
    *(u32x2_a*)(row + 16 + quad*2) = wv2;
    *(u32x2_a*)(row + 24 + quad*2) = wv3;
    bf16x8 pf1 = ldb((const unsigned short*)(p32w + lr*44 + quad*4));
    bf16x8 pf2 = ldb((const unsigned short*)(p32w + lr*44 + 16 + quad*4));

    __builtin_amdgcn_s_setprio(1);
    o[0] = __builtin_amdgcn_mfma_f32_16x16x32_bf16(v10, pf1, o[0], 0,0,0);
    o[1] = __builtin_amdgcn_mfma_f32_16x16x32_bf16(v11, pf1, o[1], 0,0,0);
    o[2] = __builtin_amdgcn_mfma_f32_16x16x32_bf16(v12, pf1, o[2], 0,0,0);
    o[3] = __builtin_amdgcn_mfma_f32_16x16x32_bf16(v13, pf1, o[3], 0,0,0);
    l4   = __builtin_amdgcn_mfma_f32_16x16x32_bf16(onesf, pf1, l4, 0,0,0);
    __builtin_amdgcn_s_setprio(0);

    // V^T chunk 2 (latency covered by PV1)
    const unsigned short* vp2 = VbT + (size_t)(hofs + lr)*2176 + j2 + quad*8;
    bf16x8 v20 = ldb(vp2), v21 = ldb(vp2 + 16*2176), v22 = ldb(vp2 + 32*2176), v23 = ldb(vp2 + 48*2176);

    __builtin_amdgcn_s_setprio(1);
    o[0] = __builtin_amdgcn_mfma_f32_16x16x32_bf16(v20, pf2, o[0], 0,0,0);
    o[1] = __builtin_amdgcn_mfma_f32_16x16x32_bf16(v21, pf2, o[1], 0,0,0);
    o[2] = __builtin_amdgcn_mfma_f32_16x16x32_bf16(v22, pf2, o[2], 0,0,0);
    o[3] = __builtin_amdgcn_mfma_f32_16x16x32_bf16(v23, pf2, o[3], 0,0,0);
    l4   = __builtin_amdgcn_mfma_f32_16x16x32_bf16(onesf, pf2, l4, 0,0,0);
    __builtin_amdgcn_s_setprio(0);
  }

  // ---- cross-wave merge ----
  float lsc = l4[0];
  __syncthreads();                       // all waves done with p32 region
  {
    float* my = (float*)shb + ((size_t)(w*64 + lane))*21;
    my[0] = m; my[1] = lsc;
    #pragma unroll
    for (int n2=0;n2<4;n2++)
      #pragma unroll
      for (int r=0;r<4;r++) my[2+n2*4+r] = o[n2][r];
  }
  __syncthreads();
  if (kh == 0){
    for (int p=1; p<nsplit; p++){
      const float* pr = (float*)shb + ((size_t)((w+p)*64 + lane))*21;
      float m2 = pr[0], l2 = pr[1];
      float M  = fmaxf(m, m2);
      float e1 = exp2f(m-M), e2 = exp2f(m2-M);
      m = M;
      lsc = lsc*e1 + l2*e2;
      #pragma unroll
      for (int n2=0;n2<4;n2++)
        #pragma unroll
        for (int r=0;r<4;r++)
          o[n2][r] = o[n2][r]*e1 + pr[2+n2*4+r]*e2;
    }
    if (isword){
      float rinv = 1.f / lsc;
      #pragma unroll
      for (int n2=0;n2<4;n2++){
        float4 sv;
        sv.x = o[n2][0]*rinv; sv.y = o[n2][1]*rinv;
        sv.z = o[n2][2]*rinv; sv.w = o[n2][3]*rinv;
        *(float4*)(outw + (size_t)(qrb+lr)*768 + hofs + n2*16 + quad*4) = sv;
      }
    } else {
      int idx = (eg*12 + h)*2 + ehalf;
      float* po = pO + (size_t)idx*1024;
      #pragma unroll
      for (int n2=0;n2<4;n2++){
        float4 sv;
        sv.x = o[n2][0]; sv.y = o[n2][1]; sv.z = o[n2][2]; sv.w = o[n2][3];
        *(float4*)(po + lr*64 + n2*16 + quad*4) = sv;
      }
      if (quad == 0){
        float* pml = pML + (size_t)idx*32;
        pml[lr*2]     = m;
        pml[lr*2 + 1] = lsc;
      }
    }
  }
}

// ---------------- entity cross-block merge: 2 key-halves -> final output ----------------
__global__ __launch_bounds__(256) void merge_ent(
    const float* __restrict__ pO, const float* __restrict__ pML,
    float* __restrict__ oute)
{
  int b = blockIdx.x;            // 0..95 = eg*12 + h
  int g = b/12, h = b%12;
  int tid = threadIdx.x;
  int row = tid>>4, cg = tid&15;
  int i0 = b*2, i1 = b*2+1;
  float m0 = pML[(size_t)i0*32 + row*2], l0 = pML[(size_t)i0*32 + row*2 + 1];
  float m1 = pML[(size_t)i1*32 + row*2], l1 = pML[(size_t)i1*32 + row*2 + 1];
  float M  = fmaxf(m0, m1);
  float e0 = exp2f(m0-M), e1 = exp2f(m1-M);
  float rl = 1.f/(l0*e0 + l1*e1);
  float4 a = *(const float4*)(pO + (size_t)i0*1024 + row*64 + cg*4);
  float4 c = *(const float4*)(pO + (size_t)i1*1024 + row*64 + cg*4);
  float4 o;
  o.x = (a.x*e0 + c.x*e1)*rl;
  o.y = (a.y*e0 + c.y*e1)*rl;
  o.z = (a.z*e0 + c.z*e1)*rl;
  o.w = (a.w*e0 + c.w*e1)*rl;
  *(float4*)(oute + (size_t)(g*16+row)*768 + h*64 + cg*4) = o;
}

extern "C" void kernel_launch(void* const* d_in, const int* in_sizes, int n_in,
                              void* d_out, int out_size, void* d_ws, size_t ws_size,
                              hipStream_t stream) {
  const float* word  = (const float*)d_in[0];
  const float* ent   = (const float*)d_in[1];
  const float* am    = (const float*)d_in[2];
  const float* q_w   = (const float*)d_in[3];
  const float* q_b   = (const float*)d_in[4];
  const float* k_w   = (const float*)d_in[5];
  const float* k_b   = (const float*)d_in[6];
  const float* v_w   = (const float*)d_in[7];
  const float* v_b   = (const float*)d_in[8];
  const float* w2e_w = (const float*)d_in[9];
  const float* w2e_b = (const float*)d_in[10];
  const float* e2w_w = (const float*)d_in[11];
  const float* e2w_b = (const float*)d_in[12];
  const float* e2e_w = (const float*)d_in[13];
  const float* e2e_b = (const float*)d_in[14];

  unsigned short* ws  = (unsigned short*)d_ws;
  unsigned short* wT  = ws;                       // 6*768*768 bf16 (dead after gemm_proj)
  unsigned short* Kb  = wT  + (size_t)6*589824;   // 2176*768
  unsigned short* Tb  = Kb  + (size_t)2176*768;   // mask tables live here (old Vb slot)
  unsigned short* Qw  = Tb  + (size_t)2176*768;   // 2048*768
  unsigned short* Qwe = Qw  + (size_t)2048*768;
  unsigned short* Qew = Qwe + (size_t)2048*768;   // 128*768
  unsigned short* Qee = Qew + (size_t)128*768;
  unsigned short* VbT = Qee + (size_t)128*768;    // 768*2176
  unsigned short* Abf = VbT + (size_t)768*2176;   // 2176*768 bf16 concat activations

  float* amT  = (float*)Tb;                       // 2176 f32
  float* negT = amT + 2176;                       // 2176 f32

  // entity partials live in the dead wT region during attention
  float* pO  = (float*)wT;                        // 192 * 16*64 f32
  float* pML = pO + (size_t)192*1024;             // 192 * 16*2  f32

  float* outw = (float*)d_out;                    // fp32 output
  float* oute = outw + (size_t)2048*768;

  hipLaunchKernelGGL(prep, dim3(24,34,8), dim3(256), 0, stream,
                     k_w, v_w, q_w, w2e_w, e2w_w, e2e_w, word, ent, am,
                     wT, Abf, amT, negT);
  hipLaunchKernelGGL(gemm_proj, dim3(68,6), dim3(256), 0, stream,
                     Abf, wT, k_b, v_b, q_b, w2e_b, e2w_b, e2e_b,
                     Kb, VbT, Qw, Qwe, Qew, Qee);
  hipLaunchKernelGGL(attn_split, dim3(80,12), dim3(256), 0, stream,
                     Kb, VbT, Qw, Qwe, Qew, Qee, amT, negT, outw, pO, pML);
  hipLaunchKernelGGL(merge_ent, dim3(96), dim3(256), 0, stream,
                     pO, pML, oute);
}

// Round 7
// 152.874 us; speedup vs baseline: 1.3555x; 1.1083x over previous
//
#include <hip/hip_runtime.h>

typedef __bf16 bf16x8 __attribute__((ext_vector_type(8)));
typedef unsigned short u16x8 __attribute__((ext_vector_type(8)));
typedef u16x8 u16x8_a __attribute__((may_alias));
typedef unsigned int u32x2 __attribute__((ext_vector_type(2)));
typedef u32x2 u32x2_a __attribute__((may_alias));
typedef unsigned int u32x4 __attribute__((ext_vector_type(4)));
typedef u32x4 u32x4_a __attribute__((may_alias));
typedef float f32x4 __attribute__((ext_vector_type(4)));
typedef float f32x16 __attribute__((ext_vector_type(16)));

#define LOG2E 1.4426950408889634f
#define NEGV  -10000.0f

// packed f32->bf16 (RNE), 2 at a time, single HW instruction
__device__ __forceinline__ unsigned int cvtpk(float lo, float hi){
  unsigned int r;
  asm("v_cvt_pk_bf16_f32 %0, %1, %2" : "=v"(r) : "v"(lo), "v"(hi));
  return r;
}
__device__ __forceinline__ bf16x8 ldb(const unsigned short* p){
  return __builtin_bit_cast(bf16x8, *(const u16x8_a*)p);
}
__device__ __forceinline__ bf16x8 mkfrag(unsigned a, unsigned b, unsigned c, unsigned d){
  u32x4 v = {a,b,c,d};
  return __builtin_bit_cast(bf16x8, v);
}
// async global->LDS, 16B per lane, dest = wave-uniform base + lane*16
__device__ __forceinline__ void gload16(const unsigned short* g, unsigned short* l){
  __builtin_amdgcn_global_load_lds(
    (const __attribute__((address_space(1))) void*)g,
    (__attribute__((address_space(3))) void*)l, 16, 0, 0);
}

// ---------------- fused prep: weight transpose+cast | A cast | mask tables ----------------
__global__ __launch_bounds__(256) void prep(
    const float* __restrict__ w0, const float* __restrict__ w1,
    const float* __restrict__ w2, const float* __restrict__ w3,
    const float* __restrict__ w4, const float* __restrict__ w5,
    const float* __restrict__ word, const float* __restrict__ ent,
    const float* __restrict__ am,
    unsigned short* __restrict__ outT, unsigned short* __restrict__ Abf,
    float* __restrict__ amT, float* __restrict__ negT)
{
  int z = blockIdx.z, tid = threadIdx.x;
  if (z == 6){
    size_t id = (size_t)blockIdx.y*24 + blockIdx.x;
    size_t e = (id*256 + tid)*8;
    const size_t WE = (size_t)2048*768;
    const float* s = (e < WE) ? (word + e) : (ent + (e - WE));
    float4 a = *(const float4*)s;
    float4 b = *(const float4*)(s+4);
    u32x4 v = {cvtpk(a.x,a.y), cvtpk(a.z,a.w), cvtpk(b.x,b.y), cvtpk(b.z,b.w)};
    *(u32x4_a*)(Abf + e) = v;
    return;
  }
  if (z == 7){
    if (blockIdx.y != 0 || blockIdx.x >= 9) return;
    int j = blockIdx.x*256 + tid;
    if (j < 2176){
      float a = am[j];
      amT[j]  = a * LOG2E;
      negT[j] = (a != 0.f) ? NEGV : 0.f;
    }
    return;
  }
  if (blockIdx.y >= 24) return;
  const float* src;
  switch (z){
    case 0: src = w0; break; case 1: src = w1; break; case 2: src = w2; break;
    case 3: src = w3; break; case 4: src = w4; break; default: src = w5; break;
  }
  unsigned short* dst = outT + (size_t)z * 589824;
  __shared__ float tile[32][33];
  int tx = tid & 31, ty = tid >> 5;
  int x0 = blockIdx.x*32, y0 = blockIdx.y*32;
  #pragma unroll
  for (int i=0;i<32;i+=8) tile[ty+i][tx] = src[(size_t)(y0+ty+i)*768 + x0+tx];
  __syncthreads();
  #pragma unroll
  for (int i=0;i<32;i+=16){
    unsigned int u = cvtpk(tile[tx][ty+i], tile[tx][ty+i+8]);
    dst[(size_t)(x0+ty+i)*768 + y0+tx]   = (unsigned short)u;
    dst[(size_t)(x0+ty+i+8)*768 + y0+tx] = (unsigned short)(u>>16);
  }
}

// ---------------- batched projection GEMM, 128x128 tiles (unchanged, known-good) ----------------
__global__ __launch_bounds__(256) void gemm_proj(
    const unsigned short* __restrict__ Abf,
    const unsigned short* __restrict__ wT,
    const float* __restrict__ bK, const float* __restrict__ bV,
    const float* __restrict__ bQ, const float* __restrict__ bWE,
    const float* __restrict__ bEW, const float* __restrict__ bEE,
    unsigned short* __restrict__ oK, unsigned short* __restrict__ VbT,
    unsigned short* __restrict__ oQ, unsigned short* __restrict__ oWE,
    unsigned short* __restrict__ oEW, unsigned short* __restrict__ oEE)
{
  int mt = blockIdx.x, ntile = blockIdx.y;
  int g, mg;
  if      (mt < 17){ g=0; mg=mt;    }
  else if (mt < 34){ g=1; mg=mt-17; }
  else if (mt < 50){ g=2; mg=mt-34; }
  else if (mt < 66){ g=3; mg=mt-50; }
  else if (mt < 67){ g=4; mg=0;     }
  else             { g=5; mg=0;     }
  int m0 = mg*128;
  const unsigned short* A = Abf + (size_t)((g>=4 ? 2048 : 0) + m0)*768;
  const unsigned short* B = wT + (size_t)g*589824;
  const float* bias; unsigned short* out;
  switch (g){
    case 0: bias=bK;  out=oK;  break;
    case 1: bias=bV;  out=0;   break;
    case 2: bias=bQ;  out=oQ;  break;
    case 3: bias=bWE; out=oWE; break;
    case 4: bias=bEW; out=oEW; break;
    default:bias=bEE; out=oEE; break;
  }
  int n0 = ntile*128;

  __shared__ __align__(16) unsigned short a_s[128*32];
  __shared__ __align__(16) unsigned short b_s[128*32];

  int tid  = threadIdx.x;
  int w    = tid>>6, lane = tid&63, quad = lane>>4, lr = lane&15;
  int wm   = (w&1)*64, wn = (w>>1)*64;

  f32x4 acc[4][4];
  #pragma unroll
  for (int i=0;i<4;i++) for (int j=0;j<4;j++) for (int r=0;r<4;r++) acc[i][j][r]=0.f;

  int srow = lane>>2;
  int scol = (lane&3)*8;
  const unsigned short* gA0 = A + (size_t)(w*32 + srow)*768 + scol;
  const unsigned short* gA1 = gA0 + (size_t)16*768;
  const unsigned short* gB0 = B + (size_t)(n0 + w*32 + srow)*768 + scol;
  const unsigned short* gB1 = gB0 + (size_t)16*768;
  unsigned short* lA0 = a_s + w*32*32;
  unsigned short* lA1 = lA0 + 16*32;
  unsigned short* lB0 = b_s + w*32*32;
  unsigned short* lB1 = lB0 + 16*32;

  for (int k0=0; k0<768; k0+=32){
    __syncthreads();
    gload16(gA0 + k0, lA0);
    gload16(gA1 + k0, lA1);
    gload16(gB0 + k0, lB0);
    gload16(gB1 + k0, lB1);
    __syncthreads();
    bf16x8 af[4], bfr[4];
    #pragma unroll
    for (int i=0;i<4;i++) af[i]  = ldb(a_s + (wm+i*16+lr)*32 + quad*8);
    #pragma unroll
    for (int j=0;j<4;j++) bfr[j] = ldb(b_s + (wn+j*16+lr)*32 + quad*8);
    #pragma unroll
    for (int i=0;i<4;i++)
      #pragma unroll
      for (int j=0;j<4;j++)
        acc[i][j] = __builtin_amdgcn_mfma_f32_16x16x32_bf16(af[i], bfr[j], acc[i][j], 0,0,0);
  }
  if (g == 1){
    #pragma unroll
    for (int j=0;j<4;j++){
      int col = n0 + wn + j*16 + lr;
      float bb = bias[col];
      #pragma unroll
      for (int i=0;i<4;i++){
        int rowb = m0 + wm + i*16 + quad*4;
        u32x2 uv = {cvtpk(acc[i][j][0]+bb, acc[i][j][1]+bb),
                    cvtpk(acc[i][j][2]+bb, acc[i][j][3]+bb)};
        *(u32x2_a*)(VbT + (size_t)col*2176 + rowb) = uv;
      }
    }
  } else {
    out += (size_t)m0*768;
    #pragma unroll
    for (int j=0;j<4;j++){
      int col = n0 + wn + j*16 + lr;
      float bb = bias[col];
      #pragma unroll
      for (int i=0;i<4;i++){
        int rowb = wm + i*16 + quad*4;
        unsigned int u01 = cvtpk(acc[i][j][0]+bb, acc[i][j][1]+bb);
        unsigned int u23 = cvtpk(acc[i][j][2]+bb, acc[i][j][3]+bb);
        out[(size_t)(rowb+0)*768 + col] = (unsigned short)u01;
        out[(size_t)(rowb+1)*768 + col] = (unsigned short)(u01>>16);
        out[(size_t)(rowb+2)*768 + col] = (unsigned short)u23;
        out[(size_t)(rowb+3)*768 + col] = (unsigned short)(u23>>16);
      }
    }
  }
}

// ---------------- 32x32 swapped-operand flash attention, fully in-register softmax ----------------
// S^T = mfma_32x32x16(K, Q): lane owns q = lane&31; its 32 keys split between lane and
// lane^32 (C-layout row = (r&3)+8*(r>>2)+4*hi). Row-max = 15 fmax + 1 shfl_xor(32).
// P^T B-frag built in-register: 8 cvt_pk + 4 shfl_xor(32) (no LDS in the loop).
// Word: 64 blocks x 32 q rows, 4-way wave key-split, in-block LDS merge.
// Entity: 16 blocks (4 q-groups x 4 key-quarters), partials to workspace, merge_ent combines.
__global__ __launch_bounds__(256) void attn_split(
  const unsigned short* __restrict__ Kb,  const unsigned short* __restrict__ VbT,
  const unsigned short* __restrict__ Qw,  const unsigned short* __restrict__ Qwe,
  const unsigned short* __restrict__ Qew, const unsigned short* __restrict__ Qee,
  const float* __restrict__ amT, const float* __restrict__ negT,
  float* __restrict__ outw, float* __restrict__ pO, float* __restrict__ pML)
{
  // XCD-aware swizzle: 960 blocks, 8 XCDs -> per-XCD contiguous head-major chunk.
  int lin = blockIdx.x + 80*blockIdx.y;
  int wid = (lin & 7)*120 + (lin >> 3);
  int bx = wid % 80;
  int h  = wid / 80;

  int tid = threadIdx.x, w = tid>>6, lane = tid&63;
  int l31 = lane & 31, hi = lane >> 5;
  int hi8 = hi*8, hi4 = hi*4;
  bool isword = bx < 64;
  int qrb, eg=0, eq=0;
  const unsigned short *Qa, *Qb;
  if (isword){ qrb = bx*32; Qa=Qw;  Qb=Qwe; }
  else       { int e = bx-64; eg = e>>2; eq = e&3; qrb = eg*32; Qa=Qew; Qb=Qee; }
  int hofs = h*64;

  __shared__ float part[4][64][35];   // epilogue merge only: m,l,o0[16],o1[16]

  // Q B-frags hoisted: lane's q row = l31, dim slice hi8 + {0,16,32,48}
  const unsigned short* qr = Qa + (size_t)(qrb+l31)*768 + hofs + hi8;
  bf16x8 qa0 = ldb(qr), qa1 = ldb(qr+16), qa2 = ldb(qr+32), qa3 = ldb(qr+48);
  qr = Qb + (size_t)(qrb+l31)*768 + hofs + hi8;
  bf16x8 qb0 = ldb(qr), qb1 = ldb(qr+16), qb2 = ldb(qr+32), qb3 = ldb(qr+48);

  float m = -1e30f, l = 0.f;
  f32x16 o0, o1;
  #pragma unroll
  for (int r=0;r<16;r++){ o0[r] = 0.f; o1[r] = 0.f; }

  int lo, nw, start, end;
  if (isword){
    lo = qrb - 256; if (lo < 0) lo = 0;
    int hiq = qrb + 288; if (hiq > 2048) hiq = 2048;
    nw = (hiq - lo) >> 5;
    start = w; end = nw + 4;
  } else {
    lo = 0; nw = 64;
    start = eq*17 + w; end = eq*17 + 17;
  }
  int iq = qrb + l31;                      // this lane's global q row

  for (int c = start; c < end; c += 4){
    bool entp = c >= nw;
    int j0 = entp ? (2048 + (c-nw)*32) : (lo + c*32);

    // K A-frags: rows = keys (l31), dims hi8 + {0,16,32,48}
    const unsigned short* kp = Kb + (size_t)(j0+l31)*768 + hofs + hi8;
    bf16x8 ka0 = ldb(kp), ka1 = ldb(kp+16), ka2 = ldb(kp+32), ka3 = ldb(kp+48);
    // V^T A-frags: rows = dims (hofs + t*32 + l31), keys j0 + kb + hi8
    const unsigned short* vp = VbT + (size_t)(hofs + l31)*2176 + j0 + hi8;
    bf16x8 va00 = ldb(vp),           va01 = ldb(vp + 16);
    bf16x8 va10 = ldb(vp + 32*2176), va11 = ldb(vp + 32*2176 + 16);
    // mask tables: lane's keys j0 + g*8 + hi4 + 0..3 per group g
    float4 aT0 = *(const float4*)(amT + j0 + hi4);
    float4 aT1 = *(const float4*)(amT + j0 + 8  + hi4);
    float4 aT2 = *(const float4*)(amT + j0 + 16 + hi4);
    float4 aT3 = *(const float4*)(amT + j0 + 24 + hi4);

    bf16x8 qf0 = entp ? qb0 : qa0, qf1 = entp ? qb1 : qa1;
    bf16x8 qf2 = entp ? qb2 : qa2, qf3 = entp ? qb3 : qa3;

    f32x16 s;
    #pragma unroll
    for (int r=0;r<16;r++) s[r] = 0.f;
    __builtin_amdgcn_s_setprio(1);
    s = __builtin_amdgcn_mfma_f32_32x32x16_bf16(ka0, qf0, s, 0,0,0);
    s = __builtin_amdgcn_mfma_f32_32x32x16_bf16(ka1, qf1, s, 0,0,0);
    s = __builtin_amdgcn_mfma_f32_32x32x16_bf16(ka2, qf2, s, 0,0,0);
    s = __builtin_amdgcn_mfma_f32_32x32x16_bf16(ka3, qf3, s, 0,0,0);
    __builtin_amdgcn_s_setprio(0);

    // scores: s[g*4+e] is key j0 + g*8 + hi4 + e for this lane's q=iq
    float sc[16];
    if (isword && !entp){
      float4 nT0 = *(const float4*)(negT + j0 + hi4);
      float4 nT1 = *(const float4*)(negT + j0 + 8  + hi4);
      float4 nT2 = *(const float4*)(negT + j0 + 16 + hi4);
      float4 nT3 = *(const float4*)(negT + j0 + 24 + hi4);
      int djb = iq + 256 - (j0 + hi4);
      #pragma unroll
      for (int e=0;e<4;e++){
        { float sv = s[e]    + nT0[e];
          bool ok = ((unsigned)(djb - e)      <= 512u) && (sv != 0.f);
          sc[e]    = (ok ? sv : NEGV) * (LOG2E*0.125f) + aT0[e]; }
        { float sv = s[4+e]  + nT1[e];
          bool ok = ((unsigned)(djb - 8 - e)  <= 512u) && (sv != 0.f);
          sc[4+e]  = (ok ? sv : NEGV) * (LOG2E*0.125f) + aT1[e]; }
        { float sv = s[8+e]  + nT2[e];
          bool ok = ((unsigned)(djb - 16 - e) <= 512u) && (sv != 0.f);
          sc[8+e]  = (ok ? sv : NEGV) * (LOG2E*0.125f) + aT2[e]; }
        { float sv = s[12+e] + nT3[e];
          bool ok = ((unsigned)(djb - 24 - e) <= 512u) && (sv != 0.f);
          sc[12+e] = (ok ? sv : NEGV) * (LOG2E*0.125f) + aT3[e]; }
      }
    } else {
      #pragma unroll
      for (int e=0;e<4;e++){
        sc[e]    = s[e]    * (LOG2E*0.125f) + aT0[e];
        sc[4+e]  = s[4+e]  * (LOG2E*0.125f) + aT1[e];
        sc[8+e]  = s[8+e]  * (LOG2E*0.125f) + aT2[e];
        sc[12+e] = s[12+e] * (LOG2E*0.125f) + aT3[e];
      }
    }

    // row max: 15 in-register fmax + 1 cross-half shuffle
    float mx = sc[0];
    #pragma unroll
    for (int r=1;r<16;r++) mx = fmaxf(mx, sc[r]);
    mx = fmaxf(mx, __shfl_xor(mx, 32));

    float mn;
    if (__all(mx <= m)){
      mn = m;                              // defer: no rescale needed
    } else {
      mn = fmaxf(m, mx);
      float alpha = exp2f(m - mn);
      m = mn;
      l *= alpha;
      #pragma unroll
      for (int r=0;r<16;r++){ o0[r] *= alpha; o1[r] *= alpha; }
    }

    float p[16];
    #pragma unroll
    for (int r=0;r<16;r++) p[r] = exp2f(sc[r]-mn);

    // l: f32 sum of own 16 + partner 16
    float rs = ((p[0]+p[1])+(p[2]+p[3])) + ((p[4]+p[5])+(p[6]+p[7]))
             + ((p[8]+p[9])+(p[10]+p[11])) + ((p[12]+p[13])+(p[14]+p[15]));
    rs += __shfl_xor(rs, 32);
    l += rs;

    // pack P to bf16 pairs (key order: pk[k] = keys crow(2k), crow(2k+1))
    unsigned pk0 = cvtpk(p[0], p[1]),  pk1 = cvtpk(p[2], p[3]);
    unsigned pk2 = cvtpk(p[4], p[5]),  pk3 = cvtpk(p[6], p[7]);
    unsigned pk4 = cvtpk(p[8], p[9]),  pk5 = cvtpk(p[10], p[11]);
    unsigned pk6 = cvtpk(p[12], p[13]),pk7 = cvtpk(p[14], p[15]);

    // cross-half exchange -> P^T B-frags (keys 0..15 and 16..31)
    bool hib = hi != 0;
    unsigned t0 = hib ? pk0 : pk2;
    unsigned t1 = hib ? pk1 : pk3;
    unsigned t2 = hib ? pk4 : pk6;
    unsigned t3 = hib ? pk5 : pk7;
    unsigned r0 = (unsigned)__shfl_xor((int)t0, 32);
    unsigned r1 = (unsigned)__shfl_xor((int)t1, 32);
    unsigned r2 = (unsigned)__shfl_xor((int)t2, 32);
    unsigned r3 = (unsigned)__shfl_xor((int)t3, 32);
    bf16x8 pf1 = hib ? mkfrag(r0, r1, pk2, pk3) : mkfrag(pk0, pk1, r0, r1);
    bf16x8 pf2 = hib ? mkfrag(r2, r3, pk6, pk7) : mkfrag(pk4, pk5, r2, r3);

    __builtin_amdgcn_s_setprio(1);
    o0 = __builtin_amdgcn_mfma_f32_32x32x16_bf16(va00, pf1, o0, 0,0,0);
    o0 = __builtin_amdgcn_mfma_f32_32x32x16_bf16(va01, pf2, o0, 0,0,0);
    o1 = __builtin_amdgcn_mfma_f32_32x32x16_bf16(va10, pf1, o1, 0,0,0);
    o1 = __builtin_amdgcn_mfma_f32_32x32x16_bf16(va11, pf2, o1, 0,0,0);
    __builtin_amdgcn_s_setprio(0);
  }

  // ---- cross-wave merge (4 key-split partials over the same 32x64 tile) ----
  {
    float* my = &part[w][lane][0];
    my[0] = m; my[1] = l;
    #pragma unroll
    for (int r=0;r<16;r++){ my[2+r] = o0[r]; my[18+r] = o1[r]; }
  }
  __syncthreads();

  float mm[4], ll[4], e4[4];
  #pragma unroll
  for (int p=0;p<4;p++){ mm[p] = part[p][lane][0]; ll[p] = part[p][lane][1]; }
  float M = fmaxf(fmaxf(mm[0],mm[1]), fmaxf(mm[2],mm[3]));
  #pragma unroll
  for (int p=0;p<4;p++) e4[p] = exp2f(mm[p]-M);
  float L = ll[0]*e4[0] + ll[1]*e4[1] + ll[2]*e4[2] + ll[3]*e4[3];

  // wave w merges and stores reg-group g=w (d = tile*32 + w*8 + hi4 + k)
  float mo0[4], mo1[4];
  #pragma unroll
  for (int k=0;k<4;k++){
    float a0 = 0.f, a1 = 0.f;
    #pragma unroll
    for (int p=0;p<4;p++){
      a0 += part[p][lane][2  + w*4 + k] * e4[p];
      a1 += part[p][lane][18 + w*4 + k] * e4[p];
    }
    mo0[k] = a0; mo1[k] = a1;
  }

  if (isword){
    float rinv = 1.f / L;
    float4 s0 = {mo0[0]*rinv, mo0[1]*rinv, mo0[2]*rinv, mo0[3]*rinv};
    float4 s1 = {mo1[0]*rinv, mo1[1]*rinv, mo1[2]*rinv, mo1[3]*rinv};
    float* ob = outw + (size_t)(qrb+l31)*768 + hofs + w*8 + hi4;
    *(float4*)(ob)      = s0;
    *(float4*)(ob + 32) = s1;
  } else {
    int idx = (eg*4 + eq)*12 + h;
    float* po = pO + (size_t)idx*2048 + l31*64 + w*8 + hi4;
    float4 s0 = {mo0[0], mo0[1], mo0[2], mo0[3]};
    float4 s1 = {mo1[0], mo1[1], mo1[2], mo1[3]};
    *(float4*)(po)      = s0;
    *(float4*)(po + 32) = s1;
    if (w == 0 && lane < 32){
      float* pml = pML + (size_t)idx*64;
      pml[lane*2]     = M;
      pml[lane*2 + 1] = L;
    }
  }
}

// ---------------- entity cross-block merge: 4 key-quarters -> final output ----------------
__global__ __launch_bounds__(256) void merge_ent(
    const float* __restrict__ pO, const float* __restrict__ pML,
    float* __restrict__ oute)
{
  int b = blockIdx.x;            // 0..47 = eg*12 + h
  int eg = b/12, h = b%12;
  int tid = threadIdx.x;
  int row = tid>>3, cg = (tid&7)*8;
  float mq[4], lq[4];
  #pragma unroll
  for (int q=0;q<4;q++){
    int idx = (eg*4 + q)*12 + h;
    mq[q] = pML[(size_t)idx*64 + row*2];
    lq[q] = pML[(size_t)idx*64 + row*2 + 1];
  }
  float M = fmaxf(fmaxf(mq[0],mq[1]), fmaxf(mq[2],mq[3]));
  float L = 0.f, eqv[4];
  #pragma unroll
  for (int q=0;q<4;q++){ eqv[q] = exp2f(mq[q]-M); L += lq[q]*eqv[q]; }
  float rl = 1.f/L;
  float4 a0 = {0,0,0,0}, a1 = {0,0,0,0};
  #pragma unroll
  for (int q=0;q<4;q++){
    int idx = (eg*4 + q)*12 + h;
    const float* src = pO + (size_t)idx*2048 + row*64 + cg;
    float4 x = *(const float4*)(src);
    float4 y = *(const float4*)(src + 4);
    a0.x += x.x*eqv[q]; a0.y += x.y*eqv[q]; a0.z += x.z*eqv[q]; a0.w += x.w*eqv[q];
    a1.x += y.x*eqv[q]; a1.y += y.y*eqv[q]; a1.z += y.z*eqv[q]; a1.w += y.w*eqv[q];
  }
  a0.x*=rl; a0.y*=rl; a0.z*=rl; a0.w*=rl;
  a1.x*=rl; a1.y*=rl; a1.z*=rl; a1.w*=rl;
  float* dst = oute + (size_t)(eg*32+row)*768 + h*64 + cg;
  *(float4*)(dst)   = a0;
  *(float4*)(dst+4) = a1;
}

extern "C" void kernel_launch(void* const* d_in, const int* in_sizes, int n_in,
                              void* d_out, int out_size, void* d_ws, size_t ws_size,
                              hipStream_t stream) {
  const float* word  = (const float*)d_in[0];
  const float* ent   = (const float*)d_in[1];
  const float* am    = (const float*)d_in[2];
  const float* q_w   = (const float*)d_in[3];
  const float* q_b   = (const float*)d_in[4];
  const float* k_w   = (const float*)d_in[5];
  const float* k_b   = (const float*)d_in[6];
  const float* v_w   = (const float*)d_in[7];
  const float* v_b   = (const float*)d_in[8];
  const float* w2e_w = (const float*)d_in[9];
  const float* w2e_b = (const float*)d_in[10];
  const float* e2w_w = (const float*)d_in[11];
  const float* e2w_b = (const float*)d_in[12];
  const float* e2e_w = (const float*)d_in[13];
  const float* e2e_b = (const float*)d_in[14];

  unsigned short* ws  = (unsigned short*)d_ws;
  unsigned short* wT  = ws;                       // 6*768*768 bf16 (dead after gemm_proj)
  unsigned short* Kb  = wT  + (size_t)6*589824;   // 2176*768
  unsigned short* Tb  = Kb  + (size_t)2176*768;   // mask tables live here
  unsigned short* Qw  = Tb  + (size_t)2176*768;   // 2048*768
  unsigned short* Qwe = Qw  + (size_t)2048*768;
  unsigned short* Qew = Qwe + (size_t)2048*768;   // 128*768
  unsigned short* Qee = Qew + (size_t)128*768;
  unsigned short* VbT = Qee + (size_t)128*768;    // 768*2176
  unsigned short* Abf = VbT + (size_t)768*2176;   // 2176*768 bf16

  float* amT  = (float*)Tb;                       // 2176 f32
  float* negT = amT + 2176;                       // 2176 f32

  // entity partials live in the dead wT region during attention
  float* pO  = (float*)wT;                        // 192 * 32*64 f32 = 1.57 MB
  float* pML = pO + (size_t)192*2048;             // 192 * 32*2  f32

  float* outw = (float*)d_out;                    // fp32 output
  float* oute = outw + (size_t)2048*768;

  hipLaunchKernelGGL(prep, dim3(24,34,8), dim3(256), 0, stream,
                     k_w, v_w, q_w, w2e_w, e2w_w, e2e_w, word, ent, am,
                     wT, Abf, amT, negT);
  hipLaunchKernelGGL(gemm_proj, dim3(68,6), dim3(256), 0, stream,
                     Abf, wT, k_b, v_b, q_b, w2e_b, e2w_b, e2e_b,
                     Kb, VbT, Qw, Qwe, Qew, Qee);
  hipLaunchKernelGGL(attn_split, dim3(80,12), dim3(256), 0, stream,
                     Kb, VbT, Qw, Qwe, Qew, Qee, amT, negT, outw, pO, pML);
  hipLaunchKernelGGL(merge_ent, dim3(48), dim3(256), 0, stream,
                     pO, pML, oute);
}